// Round 9
// baseline (156.319 us; speedup 1.0000x reference)
//
#include <hip/hip_runtime.h>
#include <hip/hip_bf16.h>

// Shapes (fixed by reference): b=2, h=8, t=8192, dh=128
#define T_SEQ   8192
#define DH      128
#define NBH     16
#define NBUCK   128
#define BSZ     64
#define EPSF    1e-6f

// K-tile swizzle (16B granular, proven in R5)
#define SWZ(r)  (((((r) & 7) ^ (((r) >> 3) & 7))) << 3)
// V-tile: pitch 72 ushorts (144B -> 4*d bank spread) + (d>>3)-keyed 16B XOR
#define VPITCH 72
#define VXOR(d) ((((d) >> 3) & 7) << 3)
// float4 / ushort4 compile-time component select (folds under full unroll)
#define CF4(v,c) ((c)==0 ? (v).x : (c)==1 ? (v).y : (c)==2 ? (v).z : (v).w)
#define CU4(v,c) ((c)==0 ? (v).x : (c)==1 ? (v).y : (c)==2 ? (v).z : (v).w)

typedef __attribute__((ext_vector_type(8))) __bf16 bf16x8;
typedef __attribute__((ext_vector_type(4))) float  f32x4;

static __device__ __forceinline__ unsigned short f2bf(float f) {
  __bf16 h = (__bf16)f;
  return __builtin_bit_cast(unsigned short, h);
}

// Fire-and-forget L2 prefetch: volatile asm load, result never consumed, so
// no s_waitcnt is tied to a use; it drains at the next barrier (covered).
static __device__ __forceinline__ void l2pf(const float* p) {
  float tmp;
  asm volatile("global_load_dword %0, %1, off" : "=v"(tmp) : "v"(p));
}

// ---------------------------------------------------------------------------
// Kernel 1: bucket sums. grid (128, 16, 2[q|k]), 256 threads. Pure streaming.
// ---------------------------------------------------------------------------
__global__ __launch_bounds__(256) void k_bsum(
    const float* __restrict__ q, const float* __restrict__ k,
    float* __restrict__ x) {
  const int u = blockIdx.x, bh = blockIdx.y, which = blockIdx.z;
  const int t = threadIdx.x;
  const int c4g = t & 31;
  const int r0  = (t >> 5) << 3;
  const float* src = which ? k : q;
  const float* p = src + ((size_t)bh * T_SEQ + (size_t)u * BSZ + r0) * DH + c4g * 4;
  float4 acc = {0.f, 0.f, 0.f, 0.f};
  #pragma unroll
  for (int r = 0; r < 8; r++) {
    float4 vv = *(const float4*)(p + (size_t)r * DH);
    acc.x += vv.x; acc.y += vv.y; acc.z += vv.z; acc.w += vv.w;
  }
  __shared__ float4 xr[8][32];
  xr[t >> 5][c4g] = acc;
  __syncthreads();
  if (t < 32) {
    float4 s4 = xr[0][t];
    #pragma unroll
    for (int j = 1; j < 8; j++) {
      float4 o = xr[j][t];
      s4.x += o.x; s4.y += o.y; s4.z += o.z; s4.w += o.w;
    }
    *(float4*)(x + ((size_t)bh * NBUCK + u) * 256 + which * 128 + t * 4) = s4;
  }
}

// ---------------------------------------------------------------------------
// Kernel 2: sortnet GEMM + relu + gumbel-log. grid (32, 16), 128 threads.
// ---------------------------------------------------------------------------
__global__ __launch_bounds__(128) void k_sortgemm(
    const float* __restrict__ x, const float* __restrict__ W,
    const float* __restrict__ ug, float* __restrict__ rbuf) {
  const int u0 = blockIdx.x * 4, bh = blockIdx.y;
  const int v = threadIdx.x;
  __shared__ float xs[4][256];
  for (int i = v; i < 1024; i += 128)
    xs[i >> 8][i & 255] = x[((size_t)bh * NBUCK + u0 + (i >> 8)) * 256 + (i & 255)];
  __syncthreads();
  const float* Wp = W + (size_t)(bh & 7) * 256 * NBUCK + v;
  float acc0 = 0.f, acc1 = 0.f, acc2 = 0.f, acc3 = 0.f;
  #pragma unroll 16
  for (int e = 0; e < 256; e++) {
    float we = Wp[(size_t)e * NBUCK];
    acc0 += xs[0][e] * we;
    acc1 += xs[1][e] * we;
    acc2 += xs[2][e] * we;
    acc3 += xs[3][e] * we;
  }
  float accs[4] = {acc0, acc1, acc2, acc3};
  #pragma unroll
  for (int j = 0; j < 4; j++) {
    float R = fmaxf(accs[j], 0.f) + EPSF;
    float gu = ug[((size_t)bh * NBUCK + u0 + j) * NBUCK + v] + EPSF;
    float g = -logf(-logf(gu) + EPSF);
    rbuf[((size_t)bh * NBUCK + u0 + j) * NBUCK + v] = (logf(R) + g) * (1.f / 0.75f);
  }
}

// ---------------------------------------------------------------------------
// Kernel 3: sinkhorn, register-resident. grid 16, 512 threads.
// ---------------------------------------------------------------------------
__global__ __launch_bounds__(512, 1) void k_sinkhorn(
    const float* __restrict__ rbuf, int* __restrict__ idxb, float* __restrict__ sb) {
  const int bh = blockIdx.x;
  const int t  = threadIdx.x;
  const int own = t >> 2;
  const int qq  = t & 3;
  __shared__ float rl[128 * 129];
  __shared__ float ca[128], ra[128];

  const float* rb = rbuf + (size_t)bh * (NBUCK * NBUCK);
  for (int i = t; i < NBUCK * NBUCK; i += 512)
    rl[(i >> 7) * 129 + (i & 127)] = rb[i];
  if (t < 128) ca[t] = 0.f;
  __syncthreads();

  float rowv[32], colv[32];
  #pragma unroll
  for (int i4 = 0; i4 < 8; i4++) {
    float4 vv = *(const float4*)(&rl[own * 129 + qq * 32 + i4 * 4]);
    rowv[i4 * 4 + 0] = vv.x; rowv[i4 * 4 + 1] = vv.y;
    rowv[i4 * 4 + 2] = vv.z; rowv[i4 * 4 + 3] = vv.w;
  }
  #pragma unroll
  for (int i = 0; i < 32; i++) colv[i] = rl[(qq * 32 + i) * 129 + own];

  for (int iter = 0; iter < 7; iter++) {
    {
      float vals[32];
      float m = -1e30f;
      #pragma unroll
      for (int i4 = 0; i4 < 8; i4++) {
        float4 cc = *(const float4*)(&ca[qq * 32 + i4 * 4]);
        vals[i4 * 4 + 0] = rowv[i4 * 4 + 0] + cc.x;
        vals[i4 * 4 + 1] = rowv[i4 * 4 + 1] + cc.y;
        vals[i4 * 4 + 2] = rowv[i4 * 4 + 2] + cc.z;
        vals[i4 * 4 + 3] = rowv[i4 * 4 + 3] + cc.w;
      }
      #pragma unroll
      for (int i = 0; i < 32; i++) m = fmaxf(m, vals[i]);
      m = fmaxf(m, __shfl_xor(m, 1));
      m = fmaxf(m, __shfl_xor(m, 2));
      float s0 = 0.f, s1 = 0.f, s2 = 0.f, s3 = 0.f;
      #pragma unroll
      for (int i = 0; i < 8; i++) {
        s0 += __expf(vals[i * 4 + 0] - m);
        s1 += __expf(vals[i * 4 + 1] - m);
        s2 += __expf(vals[i * 4 + 2] - m);
        s3 += __expf(vals[i * 4 + 3] - m);
      }
      float ss = (s0 + s1) + (s2 + s3);
      ss += __shfl_xor(ss, 1);
      ss += __shfl_xor(ss, 2);
      if (qq == 0) ra[own] = -(m + logf(ss));
    }
    __syncthreads();
    {
      float vals[32];
      float m = -1e30f;
      #pragma unroll
      for (int i4 = 0; i4 < 8; i4++) {
        float4 rr = *(const float4*)(&ra[qq * 32 + i4 * 4]);
        vals[i4 * 4 + 0] = colv[i4 * 4 + 0] + rr.x;
        vals[i4 * 4 + 1] = colv[i4 * 4 + 1] + rr.y;
        vals[i4 * 4 + 2] = colv[i4 * 4 + 2] + rr.z;
        vals[i4 * 4 + 3] = colv[i4 * 4 + 3] + rr.w;
      }
      #pragma unroll
      for (int i = 0; i < 32; i++) m = fmaxf(m, vals[i]);
      m = fmaxf(m, __shfl_xor(m, 1));
      m = fmaxf(m, __shfl_xor(m, 2));
      float s0 = 0.f, s1 = 0.f, s2 = 0.f, s3 = 0.f;
      #pragma unroll
      for (int i = 0; i < 8; i++) {
        s0 += __expf(vals[i * 4 + 0] - m);
        s1 += __expf(vals[i * 4 + 1] - m);
        s2 += __expf(vals[i * 4 + 2] - m);
        s3 += __expf(vals[i * 4 + 3] - m);
      }
      float ss = (s0 + s1) + (s2 + s3);
      ss += __shfl_xor(ss, 1);
      ss += __shfl_xor(ss, 2);
      if (qq == 0) ca[own] = -(m + logf(ss));
    }
    __syncthreads();
  }

  {
    float best = -1e30f; int bi = qq * 32;
    #pragma unroll
    for (int i = 0; i < 32; i++) {
      float val = rowv[i] + ca[qq * 32 + i];
      if (val > best) { best = val; bi = qq * 32 + i; }
    }
    #pragma unroll
    for (int d = 1; d < 4; d <<= 1) {
      float ob = __shfl_xor(best, d);
      int   oi = __shfl_xor(bi, d);
      if (ob > best || (ob == best && oi < bi)) { best = ob; bi = oi; }
    }
    if (qq == 0) {
      idxb[bh * NBUCK + own] = bi;
      sb[bh * NBUCK + own]   = expf(rl[own * 129 + bi] + ra[own] + ca[bi]);
    }
  }
}

// ---------------------------------------------------------------------------
// Kernel 4: per-bucket attention, persistent over 2 buckets.
// grid (64,16), 256 threads (4 waves); R8 internals unchanged. LDS 34816B:
//   [0,16384)     K tile [128][128], SWZ          -- dead after B2
//   [0,8192)      P [64][128], SWZ(prow)          -- after B2 (own-wave rows)
//   [8192,17408)  V half, pitch-72 + VXOR layout  -- V1 after B2, V2 after B4
// During it=0 compute, L2-prefetch it=1's K/K'/V/V'/Q (5 lines/thread,
// exact 128B-line cover of the five 32KB tiles) so it=1 staging hits L2.
// ---------------------------------------------------------------------------
__global__ __launch_bounds__(256) void k_attn(
    const float* __restrict__ q, const float* __restrict__ k, const float* __restrict__ v,
    const int* __restrict__ idxb, const float* __restrict__ sb, float* __restrict__ out) {
  const int bh = blockIdx.y;
  const int t  = threadIdx.x;
  const int lane = t & 63;
  const int w  = t >> 6;
  const int l15 = lane & 15;
  const int lgp = lane >> 4;
  const int u_base = blockIdx.x * 2;

  __shared__ uint4 smem4[2176];   // 34816 B = 17408 ushorts
  unsigned short* sm = (unsigned short*)smem4;
  #define VBASE 8192

  const size_t hb = (size_t)bh * (T_SEQ * DH);
  const float* qg = q + hb;
  const float* kg = k + hb;
  const float* vg = v + hb;

  // micro-tile coords for V staging: 4 j-rows x 8 d-cols per thread
  const int vj0 = (t >> 4) * 4;        // 0..60
  const int vd0 = (t & 15) * 8;        // 0..120

  for (int it = 0; it < 2; it++) {
    const int u = u_base + it;
    const int   vidx = idxb[bh * NBUCK + u];
    const float sval = sb[bh * NBUCK + u];

    if (it) __syncthreads();   // B0: prev PV2 V-reads done before K overwrite

    // ---- K -> LDS [0,16384) (interleaved load/cvt/store) ----
    #pragma unroll
    for (int kt = 0; kt < 16; kt++) {
      int i = kt * 256 + t;
      int row = i >> 5;
      int c4 = (i & 31) << 2;
      int grow = (row < 64) ? (vidx * BSZ + row) : (u * BSZ + (row - 64));
      float4 val = *(const float4*)(kg + (size_t)grow * DH + c4);
      ushort4 hh;
      hh.x = f2bf(val.x); hh.y = f2bf(val.y); hh.z = f2bf(val.z); hh.w = f2bf(val.w);
      *(ushort4*)(sm + (((row * 128 + c4) ^ SWZ(row)))) = hh;
    }
    // ---- Q fragments direct global -> reg ----
    bf16x8 aQ[4];
    {
      int qrow = u * BSZ + w * 16 + l15;
      const float* qp = qg + (size_t)qrow * DH + lgp * 8;
      #pragma unroll
      for (int kk = 0; kk < 4; kk++) {
        float4 v0 = *(const float4*)(qp + kk * 32);
        float4 v1 = *(const float4*)(qp + kk * 32 + 4);
        bf16x8 f;
        f[0] = (__bf16)v0.x; f[1] = (__bf16)v0.y; f[2] = (__bf16)v0.z; f[3] = (__bf16)v0.w;
        f[4] = (__bf16)v1.x; f[5] = (__bf16)v1.y; f[6] = (__bf16)v1.z; f[7] = (__bf16)v1.w;
        aQ[kk] = f;
      }
    }
    // ---- issue V half-1 loads (4 rows x 8 cols, held in regs until B2) ----
    float4 vpre[4][2];
    #pragma unroll
    for (int r = 0; r < 4; r++) {
      const float* vp = vg + (size_t)(vidx * BSZ + vj0 + r) * DH + vd0;
      vpre[r][0] = *(const float4*)(vp);
      vpre[r][1] = *(const float4*)(vp + 4);
    }
    __syncthreads();   // B1: K staged

    // ---- S = Q K^T ----
    f32x4 accS[8];
    __builtin_amdgcn_s_setprio(1);
    #pragma unroll
    for (int n = 0; n < 8; n++) {
      f32x4 acc = {0.f, 0.f, 0.f, 0.f};
      #pragma unroll
      for (int kk = 0; kk < 4; kk++) {
        int row = n * 16 + l15;
        int c0 = lgp * 8 + kk * 32;
        bf16x8 bK = *(const bf16x8*)(sm + ((row * 128 + c0) ^ SWZ(row)));
        acc = __builtin_amdgcn_mfma_f32_16x16x32_bf16(aQ[kk], bK, acc, 0, 0, 0);
      }
      accS[n] = acc;
    }
    __builtin_amdgcn_s_setprio(0);

    // ---- softmax per row ----
    float pval[8][4];
    float lsum[4];
    #pragma unroll
    for (int r = 0; r < 4; r++) {
      float mm = -1e30f;
      #pragma unroll
      for (int n = 0; n < 8; n++) {
        float lg2 = accS[n][r] * 0.03125f * (n < 4 ? sval : 1.0f);
        pval[n][r] = lg2;
        mm = fmaxf(mm, lg2);
      }
      mm = fmaxf(mm, __shfl_xor(mm, 1));
      mm = fmaxf(mm, __shfl_xor(mm, 2));
      mm = fmaxf(mm, __shfl_xor(mm, 4));
      mm = fmaxf(mm, __shfl_xor(mm, 8));
      float ss = 0.f;
      #pragma unroll
      for (int n = 0; n < 8; n++) {
        float p = __expf(pval[n][r] - mm);
        ss += p;
        pval[n][r] = p * (n < 4 ? sval : 1.0f);
      }
      ss += __shfl_xor(ss, 1);
      ss += __shfl_xor(ss, 2);
      ss += __shfl_xor(ss, 4);
      ss += __shfl_xor(ss, 8);
      lsum[r] = ss;
    }

    __syncthreads();   // B2: K dead; [0,16384) reusable

    // ---- L2 prefetch of next bucket's tiles (fire-and-forget) ----
    if (it == 0) {
      const int u_n = u_base + 1;
      const int vidx_n = idxb[bh * NBUCK + u_n];
      l2pf(kg + (size_t)(vidx_n * BSZ) * DH + t * 32);
      l2pf(kg + (size_t)(u_n    * BSZ) * DH + t * 32);
      l2pf(vg + (size_t)(vidx_n * BSZ) * DH + t * 32);
      l2pf(vg + (size_t)(u_n    * BSZ) * DH + t * 32);
      l2pf(qg + (size_t)(u_n    * BSZ) * DH + t * 32);
    }

    // ---- write P (own wave rows) into [0,8192) ----
    #pragma unroll
    for (int n = 0; n < 8; n++) {
      #pragma unroll
      for (int r = 0; r < 4; r++) {
        int prow = w * 16 + lgp * 4 + r;
        int pcol = n * 16 + l15;
        sm[(prow * 128 + pcol) ^ SWZ(prow)] = f2bf(pval[n][r]);
      }
    }
    // ---- V half-1 regs -> LDS (micro-transpose: ushort4 along j) ----
    #pragma unroll
    for (int x = 0; x < 8; x++) {
      int d = vd0 + x;
      int h = x >> 2, c = x & 3;
      ushort4 val;
      val.x = f2bf(CF4(vpre[0][h], c));
      val.y = f2bf(CF4(vpre[1][h], c));
      val.z = f2bf(CF4(vpre[2][h], c));
      val.w = f2bf(CF4(vpre[3][h], c));
      *(ushort4*)(sm + VBASE + d * VPITCH + (vj0 ^ VXOR(d))) = val;
    }
    // ---- issue V half-2 loads (convert+pack immediately) ----
    ushort4 v2p[4][2];
    #pragma unroll
    for (int r = 0; r < 4; r++) {
      const float* vp = vg + (size_t)(u * BSZ + vj0 + r) * DH + vd0;
      #pragma unroll
      for (int h = 0; h < 2; h++) {
        float4 ld = *(const float4*)(vp + h * 4);
        v2p[r][h].x = f2bf(ld.x); v2p[r][h].y = f2bf(ld.y);
        v2p[r][h].z = f2bf(ld.z); v2p[r][h].w = f2bf(ld.w);
      }
    }
    __syncthreads();   // B3: P + V1 ready

    // ---- aP fragments (own-wave rows) ----
    bf16x8 aP[4];
    #pragma unroll
    for (int kk = 0; kk < 4; kk++) {
      int prow = w * 16 + l15;
      int c0 = lgp * 8 + kk * 32;
      aP[kk] = *(const bf16x8*)(sm + ((prow * 128 + c0) ^ SWZ(prow)));
    }

    // ---- PV part 1 (j = 0..63) ----
    f32x4 accO[8];
    __builtin_amdgcn_s_setprio(1);
    #pragma unroll
    for (int n = 0; n < 8; n++) {
      f32x4 acc = {0.f, 0.f, 0.f, 0.f};
      #pragma unroll
      for (int kk = 0; kk < 2; kk++) {
        int d = n * 16 + l15;
        int jj0 = lgp * 8 + kk * 32;
        bf16x8 bV = *(const bf16x8*)(sm + VBASE + d * VPITCH + (jj0 ^ VXOR(d)));
        acc = __builtin_amdgcn_mfma_f32_16x16x32_bf16(aP[kk], bV, acc, 0, 0, 0);
      }
      accO[n] = acc;
    }
    __builtin_amdgcn_s_setprio(0);
    __syncthreads();   // B4: done reading V1

    // ---- V half-2 regs -> LDS (same micro-transpose) ----
    #pragma unroll
    for (int x = 0; x < 8; x++) {
      int d = vd0 + x;
      int h = x >> 2, c = x & 3;
      ushort4 val;
      val.x = CU4(v2p[0][h], c);
      val.y = CU4(v2p[1][h], c);
      val.z = CU4(v2p[2][h], c);
      val.w = CU4(v2p[3][h], c);
      *(ushort4*)(sm + VBASE + d * VPITCH + (vj0 ^ VXOR(d))) = val;
    }
    __syncthreads();   // B5: V2 ready

    float invl[4];
    #pragma unroll
    for (int r = 0; r < 4; r++) invl[r] = 1.0f / lsum[r];

    // ---- PV part 2 (j = 64..127) + store ----
    __builtin_amdgcn_s_setprio(1);
    #pragma unroll
    for (int n = 0; n < 8; n++) {
      f32x4 acc = accO[n];
      #pragma unroll
      for (int kk = 2; kk < 4; kk++) {
        int d = n * 16 + l15;
        int jj0 = lgp * 8 + (kk - 2) * 32;
        bf16x8 bV = *(const bf16x8*)(sm + VBASE + d * VPITCH + (jj0 ^ VXOR(d)));
        acc = __builtin_amdgcn_mfma_f32_16x16x32_bf16(aP[kk], bV, acc, 0, 0, 0);
      }
      #pragma unroll
      for (int r = 0; r < 4; r++) {
        int i2 = w * 16 + lgp * 4 + r;
        int d = n * 16 + l15;
        out[((size_t)bh * T_SEQ + (size_t)u * BSZ + i2) * DH + d] = acc[r] * invl[r];
      }
    }
    __builtin_amdgcn_s_setprio(0);
  }
}

// ---------------------------------------------------------------------------
extern "C" void kernel_launch(void* const* d_in, const int* in_sizes, int n_in,
                              void* d_out, int out_size, void* d_ws, size_t ws_size,
                              hipStream_t stream) {
  (void)in_sizes; (void)n_in; (void)out_size; (void)ws_size;
  const float* q  = (const float*)d_in[0];
  const float* k  = (const float*)d_in[1];
  const float* v  = (const float*)d_in[2];
  const float* W  = (const float*)d_in[3];
  const float* ug = (const float*)d_in[4];
  float* out = (float*)d_out;

  float* xbuf = (float*)d_ws;                                  // 2 MB
  float* rbuf = xbuf + (size_t)NBH * NBUCK * 256;              // 1 MB
  int*   idxb = (int*)(rbuf + (size_t)NBH * NBUCK * NBUCK);
  float* sb   = (float*)(idxb + NBH * NBUCK);

  k_bsum    <<<dim3(NBUCK, NBH, 2), 256, 0, stream>>>(q, k, xbuf);
  k_sortgemm<<<dim3(32, NBH),       128, 0, stream>>>(xbuf, W, ug, rbuf);
  k_sinkhorn<<<NBH,                 512, 0, stream>>>(rbuf, idxb, sb);
  k_attn    <<<dim3(64, NBH),       256, 0, stream>>>(q, k, v, idxb, sb, out);
}

// Round 10
// 111.909 us; speedup vs baseline: 1.3968x; 1.3968x over previous
//
#include <hip/hip_runtime.h>
#include <hip/hip_bf16.h>

// Shapes (fixed by reference): b=2, h=8, t=8192, dh=128
#define T_SEQ   8192
#define DH      128
#define NBH     16
#define NBUCK   128
#define BSZ     64
#define EPSF    1e-6f

// K-tile swizzle (16B granular, proven in R5)
#define SWZ(r)  (((((r) & 7) ^ (((r) >> 3) & 7))) << 3)
// V-tile: pitch 72 ushorts (144B -> 4*d bank spread) + (d>>3)-keyed 16B XOR
#define VPITCH 72
#define VXOR(d) ((((d) >> 3) & 7) << 3)
// float4 / ushort4 compile-time component select (folds under full unroll)
#define CF4(v,c) ((c)==0 ? (v).x : (c)==1 ? (v).y : (c)==2 ? (v).z : (v).w)
#define CU4(v,c) ((c)==0 ? (v).x : (c)==1 ? (v).y : (c)==2 ? (v).z : (v).w)

typedef __attribute__((ext_vector_type(8))) __bf16 bf16x8;
typedef __attribute__((ext_vector_type(4))) float  f32x4;

static __device__ __forceinline__ unsigned short f2bf(float f) {
  __bf16 h = (__bf16)f;
  return __builtin_bit_cast(unsigned short, h);
}

// ---------------------------------------------------------------------------
// Kernel 1: bucket sums. grid (128, 16, 2[q|k]), 256 threads. Pure streaming.
// ---------------------------------------------------------------------------
__global__ __launch_bounds__(256) void k_bsum(
    const float* __restrict__ q, const float* __restrict__ k,
    float* __restrict__ x) {
  const int u = blockIdx.x, bh = blockIdx.y, which = blockIdx.z;
  const int t = threadIdx.x;
  const int c4g = t & 31;
  const int r0  = (t >> 5) << 3;
  const float* src = which ? k : q;
  const float* p = src + ((size_t)bh * T_SEQ + (size_t)u * BSZ + r0) * DH + c4g * 4;
  float4 acc = {0.f, 0.f, 0.f, 0.f};
  #pragma unroll
  for (int r = 0; r < 8; r++) {
    float4 vv = *(const float4*)(p + (size_t)r * DH);
    acc.x += vv.x; acc.y += vv.y; acc.z += vv.z; acc.w += vv.w;
  }
  __shared__ float4 xr[8][32];
  xr[t >> 5][c4g] = acc;
  __syncthreads();
  if (t < 32) {
    float4 s4 = xr[0][t];
    #pragma unroll
    for (int j = 1; j < 8; j++) {
      float4 o = xr[j][t];
      s4.x += o.x; s4.y += o.y; s4.z += o.z; s4.w += o.w;
    }
    *(float4*)(x + ((size_t)bh * NBUCK + u) * 256 + which * 128 + t * 4) = s4;
  }
}

// ---------------------------------------------------------------------------
// Kernel 2: sortnet GEMM + relu + gumbel-log. grid (32, 16), 128 threads.
// ---------------------------------------------------------------------------
__global__ __launch_bounds__(128) void k_sortgemm(
    const float* __restrict__ x, const float* __restrict__ W,
    const float* __restrict__ ug, float* __restrict__ rbuf) {
  const int u0 = blockIdx.x * 4, bh = blockIdx.y;
  const int v = threadIdx.x;
  __shared__ float xs[4][256];
  for (int i = v; i < 1024; i += 128)
    xs[i >> 8][i & 255] = x[((size_t)bh * NBUCK + u0 + (i >> 8)) * 256 + (i & 255)];
  __syncthreads();
  const float* Wp = W + (size_t)(bh & 7) * 256 * NBUCK + v;
  float acc0 = 0.f, acc1 = 0.f, acc2 = 0.f, acc3 = 0.f;
  #pragma unroll 16
  for (int e = 0; e < 256; e++) {
    float we = Wp[(size_t)e * NBUCK];
    acc0 += xs[0][e] * we;
    acc1 += xs[1][e] * we;
    acc2 += xs[2][e] * we;
    acc3 += xs[3][e] * we;
  }
  float accs[4] = {acc0, acc1, acc2, acc3};
  #pragma unroll
  for (int j = 0; j < 4; j++) {
    float R = fmaxf(accs[j], 0.f) + EPSF;
    float gu = ug[((size_t)bh * NBUCK + u0 + j) * NBUCK + v] + EPSF;
    float g = -logf(-logf(gu) + EPSF);
    rbuf[((size_t)bh * NBUCK + u0 + j) * NBUCK + v] = (logf(R) + g) * (1.f / 0.75f);
  }
}

// ---------------------------------------------------------------------------
// Kernel 3: sinkhorn, register-resident. grid 16, 512 threads.
// ---------------------------------------------------------------------------
__global__ __launch_bounds__(512, 1) void k_sinkhorn(
    const float* __restrict__ rbuf, int* __restrict__ idxb, float* __restrict__ sb) {
  const int bh = blockIdx.x;
  const int t  = threadIdx.x;
  const int own = t >> 2;
  const int qq  = t & 3;
  __shared__ float rl[128 * 129];
  __shared__ float ca[128], ra[128];

  const float* rb = rbuf + (size_t)bh * (NBUCK * NBUCK);
  for (int i = t; i < NBUCK * NBUCK; i += 512)
    rl[(i >> 7) * 129 + (i & 127)] = rb[i];
  if (t < 128) ca[t] = 0.f;
  __syncthreads();

  float rowv[32], colv[32];
  #pragma unroll
  for (int i4 = 0; i4 < 8; i4++) {
    float4 vv = *(const float4*)(&rl[own * 129 + qq * 32 + i4 * 4]);
    rowv[i4 * 4 + 0] = vv.x; rowv[i4 * 4 + 1] = vv.y;
    rowv[i4 * 4 + 2] = vv.z; rowv[i4 * 4 + 3] = vv.w;
  }
  #pragma unroll
  for (int i = 0; i < 32; i++) colv[i] = rl[(qq * 32 + i) * 129 + own];

  for (int iter = 0; iter < 7; iter++) {
    {
      float vals[32];
      float m = -1e30f;
      #pragma unroll
      for (int i4 = 0; i4 < 8; i4++) {
        float4 cc = *(const float4*)(&ca[qq * 32 + i4 * 4]);
        vals[i4 * 4 + 0] = rowv[i4 * 4 + 0] + cc.x;
        vals[i4 * 4 + 1] = rowv[i4 * 4 + 1] + cc.y;
        vals[i4 * 4 + 2] = rowv[i4 * 4 + 2] + cc.z;
        vals[i4 * 4 + 3] = rowv[i4 * 4 + 3] + cc.w;
      }
      #pragma unroll
      for (int i = 0; i < 32; i++) m = fmaxf(m, vals[i]);
      m = fmaxf(m, __shfl_xor(m, 1));
      m = fmaxf(m, __shfl_xor(m, 2));
      float s0 = 0.f, s1 = 0.f, s2 = 0.f, s3 = 0.f;
      #pragma unroll
      for (int i = 0; i < 8; i++) {
        s0 += __expf(vals[i * 4 + 0] - m);
        s1 += __expf(vals[i * 4 + 1] - m);
        s2 += __expf(vals[i * 4 + 2] - m);
        s3 += __expf(vals[i * 4 + 3] - m);
      }
      float ss = (s0 + s1) + (s2 + s3);
      ss += __shfl_xor(ss, 1);
      ss += __shfl_xor(ss, 2);
      if (qq == 0) ra[own] = -(m + logf(ss));
    }
    __syncthreads();
    {
      float vals[32];
      float m = -1e30f;
      #pragma unroll
      for (int i4 = 0; i4 < 8; i4++) {
        float4 rr = *(const float4*)(&ra[qq * 32 + i4 * 4]);
        vals[i4 * 4 + 0] = colv[i4 * 4 + 0] + rr.x;
        vals[i4 * 4 + 1] = colv[i4 * 4 + 1] + rr.y;
        vals[i4 * 4 + 2] = colv[i4 * 4 + 2] + rr.z;
        vals[i4 * 4 + 3] = colv[i4 * 4 + 3] + rr.w;
      }
      #pragma unroll
      for (int i = 0; i < 32; i++) m = fmaxf(m, vals[i]);
      m = fmaxf(m, __shfl_xor(m, 1));
      m = fmaxf(m, __shfl_xor(m, 2));
      float s0 = 0.f, s1 = 0.f, s2 = 0.f, s3 = 0.f;
      #pragma unroll
      for (int i = 0; i < 8; i++) {
        s0 += __expf(vals[i * 4 + 0] - m);
        s1 += __expf(vals[i * 4 + 1] - m);
        s2 += __expf(vals[i * 4 + 2] - m);
        s3 += __expf(vals[i * 4 + 3] - m);
      }
      float ss = (s0 + s1) + (s2 + s3);
      ss += __shfl_xor(ss, 1);
      ss += __shfl_xor(ss, 2);
      if (qq == 0) ca[own] = -(m + logf(ss));
    }
    __syncthreads();
  }

  {
    float best = -1e30f; int bi = qq * 32;
    #pragma unroll
    for (int i = 0; i < 32; i++) {
      float val = rowv[i] + ca[qq * 32 + i];
      if (val > best) { best = val; bi = qq * 32 + i; }
    }
    #pragma unroll
    for (int d = 1; d < 4; d <<= 1) {
      float ob = __shfl_xor(best, d);
      int   oi = __shfl_xor(bi, d);
      if (ob > best || (ob == best && oi < bi)) { best = ob; bi = oi; }
    }
    if (qq == 0) {
      idxb[bh * NBUCK + own] = bi;
      sb[bh * NBUCK + own]   = expf(rl[own * 129 + bi] + ra[own] + ca[bi]);
    }
  }
}

// ---------------------------------------------------------------------------
// Kernel 4: per-bucket attention. grid (128,16), 256 threads (4 waves).
// R5 structure; LDS 34816B. Region map (ushort indices):
//   [0,16384)     K tile [128][128], SWZ          -- dead after B2
//   [0,8192)      P [64][128], SWZ(prow)          -- after B2 (own-wave rows)
//   [8192,17408)  V half, pitch-72 + VXOR layout  -- V1 after B2, V2 after B4
// V staged via per-thread 4jx8d register micro-transpose: ushort4 writes
// along j -> write <=2-way, b128 reads <=2-way (bank-exact by construction).
// ---------------------------------------------------------------------------
__global__ __launch_bounds__(256) void k_attn(
    const float* __restrict__ q, const float* __restrict__ k, const float* __restrict__ v,
    const int* __restrict__ idxb, const float* __restrict__ sb, float* __restrict__ out) {
  const int u  = blockIdx.x;
  const int bh = blockIdx.y;
  const int t  = threadIdx.x;
  const int lane = t & 63;
  const int w  = t >> 6;
  const int l15 = lane & 15;
  const int lgp = lane >> 4;

  __shared__ uint4 smem4[2176];   // 34816 B = 17408 ushorts
  unsigned short* sm = (unsigned short*)smem4;
  #define VBASE 8192

  const int   vidx = idxb[bh * NBUCK + u];
  const float sval = sb[bh * NBUCK + u];
  const size_t hb = (size_t)bh * (T_SEQ * DH);
  const float* qg = q + hb;
  const float* kg = k + hb;
  const float* vg = v + hb;

  // micro-tile coords for V staging: 4 j-rows x 8 d-cols per thread
  const int vj0 = (t >> 4) * 4;        // 0..60
  const int vd0 = (t & 15) * 8;        // 0..120

  // ---- K -> LDS [0,16384) (interleaved load/cvt/store) ----
  #pragma unroll
  for (int it = 0; it < 16; it++) {
    int i = it * 256 + t;
    int row = i >> 5;
    int c4 = (i & 31) << 2;
    int grow = (row < 64) ? (vidx * BSZ + row) : (u * BSZ + (row - 64));
    float4 val = *(const float4*)(kg + (size_t)grow * DH + c4);
    ushort4 hh;
    hh.x = f2bf(val.x); hh.y = f2bf(val.y); hh.z = f2bf(val.z); hh.w = f2bf(val.w);
    *(ushort4*)(sm + (((row * 128 + c4) ^ SWZ(row)))) = hh;
  }
  // ---- Q fragments direct global -> reg ----
  bf16x8 aQ[4];
  {
    int qrow = u * BSZ + w * 16 + l15;
    const float* qp = qg + (size_t)qrow * DH + lgp * 8;
    #pragma unroll
    for (int kk = 0; kk < 4; kk++) {
      float4 v0 = *(const float4*)(qp + kk * 32);
      float4 v1 = *(const float4*)(qp + kk * 32 + 4);
      bf16x8 f;
      f[0] = (__bf16)v0.x; f[1] = (__bf16)v0.y; f[2] = (__bf16)v0.z; f[3] = (__bf16)v0.w;
      f[4] = (__bf16)v1.x; f[5] = (__bf16)v1.y; f[6] = (__bf16)v1.z; f[7] = (__bf16)v1.w;
      aQ[kk] = f;
    }
  }
  // ---- issue V half-1 loads (4 rows x 8 cols, held in regs until B2) ----
  float4 vpre[4][2];
  #pragma unroll
  for (int r = 0; r < 4; r++) {
    const float* vp = vg + (size_t)(vidx * BSZ + vj0 + r) * DH + vd0;
    vpre[r][0] = *(const float4*)(vp);
    vpre[r][1] = *(const float4*)(vp + 4);
  }
  __syncthreads();   // B1: K staged

  // ---- S = Q K^T ----
  f32x4 accS[8];
  __builtin_amdgcn_s_setprio(1);
  #pragma unroll
  for (int n = 0; n < 8; n++) {
    f32x4 acc = {0.f, 0.f, 0.f, 0.f};
    #pragma unroll
    for (int kk = 0; kk < 4; kk++) {
      int row = n * 16 + l15;
      int c0 = lgp * 8 + kk * 32;
      bf16x8 bK = *(const bf16x8*)(sm + ((row * 128 + c0) ^ SWZ(row)));
      acc = __builtin_amdgcn_mfma_f32_16x16x32_bf16(aQ[kk], bK, acc, 0, 0, 0);
    }
    accS[n] = acc;
  }
  __builtin_amdgcn_s_setprio(0);

  // ---- softmax per row ----
  float pval[8][4];
  float lsum[4];
  #pragma unroll
  for (int r = 0; r < 4; r++) {
    float mm = -1e30f;
    #pragma unroll
    for (int n = 0; n < 8; n++) {
      float lg2 = accS[n][r] * 0.03125f * (n < 4 ? sval : 1.0f);
      pval[n][r] = lg2;
      mm = fmaxf(mm, lg2);
    }
    mm = fmaxf(mm, __shfl_xor(mm, 1));
    mm = fmaxf(mm, __shfl_xor(mm, 2));
    mm = fmaxf(mm, __shfl_xor(mm, 4));
    mm = fmaxf(mm, __shfl_xor(mm, 8));
    float ss = 0.f;
    #pragma unroll
    for (int n = 0; n < 8; n++) {
      float p = __expf(pval[n][r] - mm);
      ss += p;
      pval[n][r] = p * (n < 4 ? sval : 1.0f);
    }
    ss += __shfl_xor(ss, 1);
    ss += __shfl_xor(ss, 2);
    ss += __shfl_xor(ss, 4);
    ss += __shfl_xor(ss, 8);
    lsum[r] = ss;
  }

  __syncthreads();   // B2: K dead; [0,16384) reusable

  // ---- write P (own wave rows) into [0,8192) ----
  #pragma unroll
  for (int n = 0; n < 8; n++) {
    #pragma unroll
    for (int r = 0; r < 4; r++) {
      int prow = w * 16 + lgp * 4 + r;
      int pcol = n * 16 + l15;
      sm[(prow * 128 + pcol) ^ SWZ(prow)] = f2bf(pval[n][r]);
    }
  }
  // ---- V half-1 regs -> LDS (micro-transpose: ushort4 along j) ----
  #pragma unroll
  for (int x = 0; x < 8; x++) {
    int d = vd0 + x;
    int h = x >> 2, c = x & 3;
    ushort4 val;
    val.x = f2bf(CF4(vpre[0][h], c));
    val.y = f2bf(CF4(vpre[1][h], c));
    val.z = f2bf(CF4(vpre[2][h], c));
    val.w = f2bf(CF4(vpre[3][h], c));
    *(ushort4*)(sm + VBASE + d * VPITCH + (vj0 ^ VXOR(d))) = val;
  }
  // ---- issue V half-2 loads (convert+pack immediately; 16 VGPR B2->B4) ----
  ushort4 v2p[4][2];
  #pragma unroll
  for (int r = 0; r < 4; r++) {
    const float* vp = vg + (size_t)(u * BSZ + vj0 + r) * DH + vd0;
    #pragma unroll
    for (int h = 0; h < 2; h++) {
      float4 ld = *(const float4*)(vp + h * 4);
      v2p[r][h].x = f2bf(ld.x); v2p[r][h].y = f2bf(ld.y);
      v2p[r][h].z = f2bf(ld.z); v2p[r][h].w = f2bf(ld.w);
    }
  }
  __syncthreads();   // B3: P + V1 ready

  // ---- aP fragments (own-wave rows) ----
  bf16x8 aP[4];
  #pragma unroll
  for (int kk = 0; kk < 4; kk++) {
    int prow = w * 16 + l15;
    int c0 = lgp * 8 + kk * 32;
    aP[kk] = *(const bf16x8*)(sm + ((prow * 128 + c0) ^ SWZ(prow)));
  }

  // ---- PV part 1 (j = 0..63) ----
  f32x4 accO[8];
  __builtin_amdgcn_s_setprio(1);
  #pragma unroll
  for (int n = 0; n < 8; n++) {
    f32x4 acc = {0.f, 0.f, 0.f, 0.f};
    #pragma unroll
    for (int kk = 0; kk < 2; kk++) {
      int d = n * 16 + l15;
      int jj0 = lgp * 8 + kk * 32;
      bf16x8 bV = *(const bf16x8*)(sm + VBASE + d * VPITCH + (jj0 ^ VXOR(d)));
      acc = __builtin_amdgcn_mfma_f32_16x16x32_bf16(aP[kk], bV, acc, 0, 0, 0);
    }
    accO[n] = acc;
  }
  __builtin_amdgcn_s_setprio(0);
  __syncthreads();   // B4: done reading V1

  // ---- V half-2 regs -> LDS (same micro-transpose) ----
  #pragma unroll
  for (int x = 0; x < 8; x++) {
    int d = vd0 + x;
    int h = x >> 2, c = x & 3;
    ushort4 val;
    val.x = CU4(v2p[0][h], c);
    val.y = CU4(v2p[1][h], c);
    val.z = CU4(v2p[2][h], c);
    val.w = CU4(v2p[3][h], c);
    *(ushort4*)(sm + VBASE + d * VPITCH + (vj0 ^ VXOR(d))) = val;
  }
  __syncthreads();   // B5: V2 ready

  float invl[4];
  #pragma unroll
  for (int r = 0; r < 4; r++) invl[r] = 1.0f / lsum[r];

  // ---- PV part 2 (j = 64..127) + store ----
  __builtin_amdgcn_s_setprio(1);
  #pragma unroll
  for (int n = 0; n < 8; n++) {
    f32x4 acc = accO[n];
    #pragma unroll
    for (int kk = 2; kk < 4; kk++) {
      int d = n * 16 + l15;
      int jj0 = lgp * 8 + (kk - 2) * 32;
      bf16x8 bV = *(const bf16x8*)(sm + VBASE + d * VPITCH + (jj0 ^ VXOR(d)));
      acc = __builtin_amdgcn_mfma_f32_16x16x32_bf16(aP[kk], bV, acc, 0, 0, 0);
    }
    #pragma unroll
    for (int r = 0; r < 4; r++) {
      int i2 = w * 16 + lgp * 4 + r;
      int d = n * 16 + l15;
      out[((size_t)bh * T_SEQ + (size_t)u * BSZ + i2) * DH + d] = acc[r] * invl[r];
    }
  }
  __builtin_amdgcn_s_setprio(0);
}

// ---------------------------------------------------------------------------
extern "C" void kernel_launch(void* const* d_in, const int* in_sizes, int n_in,
                              void* d_out, int out_size, void* d_ws, size_t ws_size,
                              hipStream_t stream) {
  (void)in_sizes; (void)n_in; (void)out_size; (void)ws_size;
  const float* q  = (const float*)d_in[0];
  const float* k  = (const float*)d_in[1];
  const float* v  = (const float*)d_in[2];
  const float* W  = (const float*)d_in[3];
  const float* ug = (const float*)d_in[4];
  float* out = (float*)d_out;

  float* xbuf = (float*)d_ws;                                  // 2 MB
  float* rbuf = xbuf + (size_t)NBH * NBUCK * 256;              // 1 MB
  int*   idxb = (int*)(rbuf + (size_t)NBH * NBUCK * NBUCK);
  float* sb   = (float*)(idxb + NBH * NBUCK);

  k_bsum    <<<dim3(NBUCK, NBH, 2), 256, 0, stream>>>(q, k, xbuf);
  k_sortgemm<<<dim3(32, NBH),       128, 0, stream>>>(xbuf, W, ug, rbuf);
  k_sinkhorn<<<NBH,                 512, 0, stream>>>(rbuf, idxb, sb);
  k_attn    <<<dim3(NBUCK, NBH),    256, 0, stream>>>(q, k, v, idxb, sb, out);
}

// Round 11
// 111.820 us; speedup vs baseline: 1.3979x; 1.0008x over previous
//
#include <hip/hip_runtime.h>
#include <hip/hip_bf16.h>

// Shapes (fixed by reference): b=2, h=8, t=8192, dh=128
#define T_SEQ   8192
#define DH      128
#define NBH     16
#define NBUCK   128
#define BSZ     64
#define EPSF    1e-6f

// K-tile swizzle (16B granular, proven in R5)
#define SWZ(r)  (((((r) & 7) ^ (((r) >> 3) & 7))) << 3)
// V-tile: pitch 72 ushorts (144B -> 4*d bank spread) + (d>>3)-keyed 16B XOR
#define VPITCH 72
#define VXOR(d) ((((d) >> 3) & 7) << 3)
// float4 / ushort4 compile-time component select (folds under full unroll)
#define CF4(v,c) ((c)==0 ? (v).x : (c)==1 ? (v).y : (c)==2 ? (v).z : (v).w)
#define CU4(v,c) ((c)==0 ? (v).x : (c)==1 ? (v).y : (c)==2 ? (v).z : (v).w)

typedef __attribute__((ext_vector_type(8))) __bf16 bf16x8;
typedef __attribute__((ext_vector_type(4))) float  f32x4;

static __device__ __forceinline__ unsigned short f2bf(float f) {
  __bf16 h = (__bf16)f;
  return __builtin_bit_cast(unsigned short, h);
}

// ---------------------------------------------------------------------------
// Kernel 1: bucket sums. grid (128, 16, 2[q|k]), 256 threads. Pure streaming.
// ---------------------------------------------------------------------------
__global__ __launch_bounds__(256) void k_bsum(
    const float* __restrict__ q, const float* __restrict__ k,
    float* __restrict__ x) {
  const int u = blockIdx.x, bh = blockIdx.y, which = blockIdx.z;
  const int t = threadIdx.x;
  const int c4g = t & 31;
  const int r0  = (t >> 5) << 3;
  const float* src = which ? k : q;
  const float* p = src + ((size_t)bh * T_SEQ + (size_t)u * BSZ + r0) * DH + c4g * 4;
  float4 acc = {0.f, 0.f, 0.f, 0.f};
  #pragma unroll
  for (int r = 0; r < 8; r++) {
    float4 vv = *(const float4*)(p + (size_t)r * DH);
    acc.x += vv.x; acc.y += vv.y; acc.z += vv.z; acc.w += vv.w;
  }
  __shared__ float4 xr[8][32];
  xr[t >> 5][c4g] = acc;
  __syncthreads();
  if (t < 32) {
    float4 s4 = xr[0][t];
    #pragma unroll
    for (int j = 1; j < 8; j++) {
      float4 o = xr[j][t];
      s4.x += o.x; s4.y += o.y; s4.z += o.z; s4.w += o.w;
    }
    *(float4*)(x + ((size_t)bh * NBUCK + u) * 256 + which * 128 + t * 4) = s4;
  }
}

// ---------------------------------------------------------------------------
// Kernel 2: sortnet GEMM + relu + gumbel-log. grid (32, 16), 128 threads.
// ---------------------------------------------------------------------------
__global__ __launch_bounds__(128) void k_sortgemm(
    const float* __restrict__ x, const float* __restrict__ W,
    const float* __restrict__ ug, float* __restrict__ rbuf) {
  const int u0 = blockIdx.x * 4, bh = blockIdx.y;
  const int v = threadIdx.x;
  __shared__ float xs[4][256];
  for (int i = v; i < 1024; i += 128)
    xs[i >> 8][i & 255] = x[((size_t)bh * NBUCK + u0 + (i >> 8)) * 256 + (i & 255)];
  __syncthreads();
  const float* Wp = W + (size_t)(bh & 7) * 256 * NBUCK + v;
  float acc0 = 0.f, acc1 = 0.f, acc2 = 0.f, acc3 = 0.f;
  #pragma unroll 16
  for (int e = 0; e < 256; e++) {
    float we = Wp[(size_t)e * NBUCK];
    acc0 += xs[0][e] * we;
    acc1 += xs[1][e] * we;
    acc2 += xs[2][e] * we;
    acc3 += xs[3][e] * we;
  }
  float accs[4] = {acc0, acc1, acc2, acc3};
  #pragma unroll
  for (int j = 0; j < 4; j++) {
    float R = fmaxf(accs[j], 0.f) + EPSF;
    float gu = ug[((size_t)bh * NBUCK + u0 + j) * NBUCK + v] + EPSF;
    float g = -logf(-logf(gu) + EPSF);
    rbuf[((size_t)bh * NBUCK + u0 + j) * NBUCK + v] = (logf(R) + g) * (1.f / 0.75f);
  }
}

// ---------------------------------------------------------------------------
// Kernel 3: sinkhorn, register-resident. grid 16, 512 threads.
// ---------------------------------------------------------------------------
__global__ __launch_bounds__(512, 1) void k_sinkhorn(
    const float* __restrict__ rbuf, int* __restrict__ idxb, float* __restrict__ sb) {
  const int bh = blockIdx.x;
  const int t  = threadIdx.x;
  const int own = t >> 2;
  const int qq  = t & 3;
  __shared__ float rl[128 * 129];
  __shared__ float ca[128], ra[128];

  const float* rb = rbuf + (size_t)bh * (NBUCK * NBUCK);
  for (int i = t; i < NBUCK * NBUCK; i += 512)
    rl[(i >> 7) * 129 + (i & 127)] = rb[i];
  if (t < 128) ca[t] = 0.f;
  __syncthreads();

  float rowv[32], colv[32];
  #pragma unroll
  for (int i4 = 0; i4 < 8; i4++) {
    float4 vv = *(const float4*)(&rl[own * 129 + qq * 32 + i4 * 4]);
    rowv[i4 * 4 + 0] = vv.x; rowv[i4 * 4 + 1] = vv.y;
    rowv[i4 * 4 + 2] = vv.z; rowv[i4 * 4 + 3] = vv.w;
  }
  #pragma unroll
  for (int i = 0; i < 32; i++) colv[i] = rl[(qq * 32 + i) * 129 + own];

  for (int iter = 0; iter < 7; iter++) {
    {
      float vals[32];
      float m = -1e30f;
      #pragma unroll
      for (int i4 = 0; i4 < 8; i4++) {
        float4 cc = *(const float4*)(&ca[qq * 32 + i4 * 4]);
        vals[i4 * 4 + 0] = rowv[i4 * 4 + 0] + cc.x;
        vals[i4 * 4 + 1] = rowv[i4 * 4 + 1] + cc.y;
        vals[i4 * 4 + 2] = rowv[i4 * 4 + 2] + cc.z;
        vals[i4 * 4 + 3] = rowv[i4 * 4 + 3] + cc.w;
      }
      #pragma unroll
      for (int i = 0; i < 32; i++) m = fmaxf(m, vals[i]);
      m = fmaxf(m, __shfl_xor(m, 1));
      m = fmaxf(m, __shfl_xor(m, 2));
      float s0 = 0.f, s1 = 0.f, s2 = 0.f, s3 = 0.f;
      #pragma unroll
      for (int i = 0; i < 8; i++) {
        s0 += __expf(vals[i * 4 + 0] - m);
        s1 += __expf(vals[i * 4 + 1] - m);
        s2 += __expf(vals[i * 4 + 2] - m);
        s3 += __expf(vals[i * 4 + 3] - m);
      }
      float ss = (s0 + s1) + (s2 + s3);
      ss += __shfl_xor(ss, 1);
      ss += __shfl_xor(ss, 2);
      if (qq == 0) ra[own] = -(m + logf(ss));
    }
    __syncthreads();
    {
      float vals[32];
      float m = -1e30f;
      #pragma unroll
      for (int i4 = 0; i4 < 8; i4++) {
        float4 rr = *(const float4*)(&ra[qq * 32 + i4 * 4]);
        vals[i4 * 4 + 0] = colv[i4 * 4 + 0] + rr.x;
        vals[i4 * 4 + 1] = colv[i4 * 4 + 1] + rr.y;
        vals[i4 * 4 + 2] = colv[i4 * 4 + 2] + rr.z;
        vals[i4 * 4 + 3] = colv[i4 * 4 + 3] + rr.w;
      }
      #pragma unroll
      for (int i = 0; i < 32; i++) m = fmaxf(m, vals[i]);
      m = fmaxf(m, __shfl_xor(m, 1));
      m = fmaxf(m, __shfl_xor(m, 2));
      float s0 = 0.f, s1 = 0.f, s2 = 0.f, s3 = 0.f;
      #pragma unroll
      for (int i = 0; i < 8; i++) {
        s0 += __expf(vals[i * 4 + 0] - m);
        s1 += __expf(vals[i * 4 + 1] - m);
        s2 += __expf(vals[i * 4 + 2] - m);
        s3 += __expf(vals[i * 4 + 3] - m);
      }
      float ss = (s0 + s1) + (s2 + s3);
      ss += __shfl_xor(ss, 1);
      ss += __shfl_xor(ss, 2);
      if (qq == 0) ca[own] = -(m + logf(ss));
    }
    __syncthreads();
  }

  {
    float best = -1e30f; int bi = qq * 32;
    #pragma unroll
    for (int i = 0; i < 32; i++) {
      float val = rowv[i] + ca[qq * 32 + i];
      if (val > best) { best = val; bi = qq * 32 + i; }
    }
    #pragma unroll
    for (int d = 1; d < 4; d <<= 1) {
      float ob = __shfl_xor(best, d);
      int   oi = __shfl_xor(bi, d);
      if (ob > best || (ob == best && oi < bi)) { best = ob; bi = oi; }
    }
    if (qq == 0) {
      idxb[bh * NBUCK + own] = bi;
      sb[bh * NBUCK + own]   = expf(rl[own * 129 + bi] + ra[own] + ca[bi]);
    }
  }
}

// ---------------------------------------------------------------------------
// Kernel 4: per-bucket attention. grid (16 bh, 128 bucket), 256 threads.
// GRID TRANSPOSED for XCD L2 locality: linear id = bh + 16*u -> XCD = bh%8,
// so each XCD serves only 2 bh (vidx gathers + K/V reuse become L2-local).
// Kernel internals identical to the measured optimum (R8/R10). LDS 34816B:
//   [0,16384)     K tile [128][128], SWZ          -- dead after B2
//   [0,8192)      P [64][128], SWZ(prow)          -- after B2 (own-wave rows)
//   [8192,17408)  V half, pitch-72 + VXOR layout  -- V1 after B2, V2 after B4
// ---------------------------------------------------------------------------
__global__ __launch_bounds__(256) void k_attn(
    const float* __restrict__ q, const float* __restrict__ k, const float* __restrict__ v,
    const int* __restrict__ idxb, const float* __restrict__ sb, float* __restrict__ out) {
  const int bh = blockIdx.x;    // transposed: bh on x -> XCD = bh % 8
  const int u  = blockIdx.y;
  const int t  = threadIdx.x;
  const int lane = t & 63;
  const int w  = t >> 6;
  const int l15 = lane & 15;
  const int lgp = lane >> 4;

  __shared__ uint4 smem4[2176];   // 34816 B = 17408 ushorts
  unsigned short* sm = (unsigned short*)smem4;
  #define VBASE 8192

  const int   vidx = idxb[bh * NBUCK + u];
  const float sval = sb[bh * NBUCK + u];
  const size_t hb = (size_t)bh * (T_SEQ * DH);
  const float* qg = q + hb;
  const float* kg = k + hb;
  const float* vg = v + hb;

  // micro-tile coords for V staging: 4 j-rows x 8 d-cols per thread
  const int vj0 = (t >> 4) * 4;        // 0..60
  const int vd0 = (t & 15) * 8;        // 0..120

  // ---- K -> LDS [0,16384) (interleaved load/cvt/store) ----
  #pragma unroll
  for (int it = 0; it < 16; it++) {
    int i = it * 256 + t;
    int row = i >> 5;
    int c4 = (i & 31) << 2;
    int grow = (row < 64) ? (vidx * BSZ + row) : (u * BSZ + (row - 64));
    float4 val = *(const float4*)(kg + (size_t)grow * DH + c4);
    ushort4 hh;
    hh.x = f2bf(val.x); hh.y = f2bf(val.y); hh.z = f2bf(val.z); hh.w = f2bf(val.w);
    *(ushort4*)(sm + (((row * 128 + c4) ^ SWZ(row)))) = hh;
  }
  // ---- Q fragments direct global -> reg ----
  bf16x8 aQ[4];
  {
    int qrow = u * BSZ + w * 16 + l15;
    const float* qp = qg + (size_t)qrow * DH + lgp * 8;
    #pragma unroll
    for (int kk = 0; kk < 4; kk++) {
      float4 v0 = *(const float4*)(qp + kk * 32);
      float4 v1 = *(const float4*)(qp + kk * 32 + 4);
      bf16x8 f;
      f[0] = (__bf16)v0.x; f[1] = (__bf16)v0.y; f[2] = (__bf16)v0.z; f[3] = (__bf16)v0.w;
      f[4] = (__bf16)v1.x; f[5] = (__bf16)v1.y; f[6] = (__bf16)v1.z; f[7] = (__bf16)v1.w;
      aQ[kk] = f;
    }
  }
  // ---- issue V half-1 loads (4 rows x 8 cols, held in regs until B2) ----
  float4 vpre[4][2];
  #pragma unroll
  for (int r = 0; r < 4; r++) {
    const float* vp = vg + (size_t)(vidx * BSZ + vj0 + r) * DH + vd0;
    vpre[r][0] = *(const float4*)(vp);
    vpre[r][1] = *(const float4*)(vp + 4);
  }
  __syncthreads();   // B1: K staged

  // ---- S = Q K^T ----
  f32x4 accS[8];
  __builtin_amdgcn_s_setprio(1);
  #pragma unroll
  for (int n = 0; n < 8; n++) {
    f32x4 acc = {0.f, 0.f, 0.f, 0.f};
    #pragma unroll
    for (int kk = 0; kk < 4; kk++) {
      int row = n * 16 + l15;
      int c0 = lgp * 8 + kk * 32;
      bf16x8 bK = *(const bf16x8*)(sm + ((row * 128 + c0) ^ SWZ(row)));
      acc = __builtin_amdgcn_mfma_f32_16x16x32_bf16(aQ[kk], bK, acc, 0, 0, 0);
    }
    accS[n] = acc;
  }
  __builtin_amdgcn_s_setprio(0);

  // ---- softmax per row ----
  float pval[8][4];
  float lsum[4];
  #pragma unroll
  for (int r = 0; r < 4; r++) {
    float mm = -1e30f;
    #pragma unroll
    for (int n = 0; n < 8; n++) {
      float lg2 = accS[n][r] * 0.03125f * (n < 4 ? sval : 1.0f);
      pval[n][r] = lg2;
      mm = fmaxf(mm, lg2);
    }
    mm = fmaxf(mm, __shfl_xor(mm, 1));
    mm = fmaxf(mm, __shfl_xor(mm, 2));
    mm = fmaxf(mm, __shfl_xor(mm, 4));
    mm = fmaxf(mm, __shfl_xor(mm, 8));
    float ss = 0.f;
    #pragma unroll
    for (int n = 0; n < 8; n++) {
      float p = __expf(pval[n][r] - mm);
      ss += p;
      pval[n][r] = p * (n < 4 ? sval : 1.0f);
    }
    ss += __shfl_xor(ss, 1);
    ss += __shfl_xor(ss, 2);
    ss += __shfl_xor(ss, 4);
    ss += __shfl_xor(ss, 8);
    lsum[r] = ss;
  }

  __syncthreads();   // B2: K dead; [0,16384) reusable

  // ---- write P (own wave rows) into [0,8192) ----
  #pragma unroll
  for (int n = 0; n < 8; n++) {
    #pragma unroll
    for (int r = 0; r < 4; r++) {
      int prow = w * 16 + lgp * 4 + r;
      int pcol = n * 16 + l15;
      sm[(prow * 128 + pcol) ^ SWZ(prow)] = f2bf(pval[n][r]);
    }
  }
  // ---- V half-1 regs -> LDS (micro-transpose: ushort4 along j) ----
  #pragma unroll
  for (int x = 0; x < 8; x++) {
    int d = vd0 + x;
    int h = x >> 2, c = x & 3;
    ushort4 val;
    val.x = f2bf(CF4(vpre[0][h], c));
    val.y = f2bf(CF4(vpre[1][h], c));
    val.z = f2bf(CF4(vpre[2][h], c));
    val.w = f2bf(CF4(vpre[3][h], c));
    *(ushort4*)(sm + VBASE + d * VPITCH + (vj0 ^ VXOR(d))) = val;
  }
  // ---- issue V half-2 loads (convert+pack immediately; 16 VGPR B2->B4) ----
  ushort4 v2p[4][2];
  #pragma unroll
  for (int r = 0; r < 4; r++) {
    const float* vp = vg + (size_t)(u * BSZ + vj0 + r) * DH + vd0;
    #pragma unroll
    for (int h = 0; h < 2; h++) {
      float4 ld = *(const float4*)(vp + h * 4);
      v2p[r][h].x = f2bf(ld.x); v2p[r][h].y = f2bf(ld.y);
      v2p[r][h].z = f2bf(ld.z); v2p[r][h].w = f2bf(ld.w);
    }
  }
  __syncthreads();   // B3: P + V1 ready

  // ---- aP fragments (own-wave rows) ----
  bf16x8 aP[4];
  #pragma unroll
  for (int kk = 0; kk < 4; kk++) {
    int prow = w * 16 + l15;
    int c0 = lgp * 8 + kk * 32;
    aP[kk] = *(const bf16x8*)(sm + ((prow * 128 + c0) ^ SWZ(prow)));
  }

  // ---- PV part 1 (j = 0..63) ----
  f32x4 accO[8];
  __builtin_amdgcn_s_setprio(1);
  #pragma unroll
  for (int n = 0; n < 8; n++) {
    f32x4 acc = {0.f, 0.f, 0.f, 0.f};
    #pragma unroll
    for (int kk = 0; kk < 2; kk++) {
      int d = n * 16 + l15;
      int jj0 = lgp * 8 + kk * 32;
      bf16x8 bV = *(const bf16x8*)(sm + VBASE + d * VPITCH + (jj0 ^ VXOR(d)));
      acc = __builtin_amdgcn_mfma_f32_16x16x32_bf16(aP[kk], bV, acc, 0, 0, 0);
    }
    accO[n] = acc;
  }
  __builtin_amdgcn_s_setprio(0);
  __syncthreads();   // B4: done reading V1

  // ---- V half-2 regs -> LDS (same micro-transpose) ----
  #pragma unroll
  for (int x = 0; x < 8; x++) {
    int d = vd0 + x;
    int h = x >> 2, c = x & 3;
    ushort4 val;
    val.x = CU4(v2p[0][h], c);
    val.y = CU4(v2p[1][h], c);
    val.z = CU4(v2p[2][h], c);
    val.w = CU4(v2p[3][h], c);
    *(ushort4*)(sm + VBASE + d * VPITCH + (vj0 ^ VXOR(d))) = val;
  }
  __syncthreads();   // B5: V2 ready

  float invl[4];
  #pragma unroll
  for (int r = 0; r < 4; r++) invl[r] = 1.0f / lsum[r];

  // ---- PV part 2 (j = 64..127) + store ----
  __builtin_amdgcn_s_setprio(1);
  #pragma unroll
  for (int n = 0; n < 8; n++) {
    f32x4 acc = accO[n];
    #pragma unroll
    for (int kk = 2; kk < 4; kk++) {
      int d = n * 16 + l15;
      int jj0 = lgp * 8 + (kk - 2) * 32;
      bf16x8 bV = *(const bf16x8*)(sm + VBASE + d * VPITCH + (jj0 ^ VXOR(d)));
      acc = __builtin_amdgcn_mfma_f32_16x16x32_bf16(aP[kk], bV, acc, 0, 0, 0);
    }
    #pragma unroll
    for (int r = 0; r < 4; r++) {
      int i2 = w * 16 + lgp * 4 + r;
      int d = n * 16 + l15;
      out[((size_t)bh * T_SEQ + (size_t)u * BSZ + i2) * DH + d] = acc[r] * invl[r];
    }
  }
  __builtin_amdgcn_s_setprio(0);
}

// ---------------------------------------------------------------------------
extern "C" void kernel_launch(void* const* d_in, const int* in_sizes, int n_in,
                              void* d_out, int out_size, void* d_ws, size_t ws_size,
                              hipStream_t stream) {
  (void)in_sizes; (void)n_in; (void)out_size; (void)ws_size;
  const float* q  = (const float*)d_in[0];
  const float* k  = (const float*)d_in[1];
  const float* v  = (const float*)d_in[2];
  const float* W  = (const float*)d_in[3];
  const float* ug = (const float*)d_in[4];
  float* out = (float*)d_out;

  float* xbuf = (float*)d_ws;                                  // 2 MB
  float* rbuf = xbuf + (size_t)NBH * NBUCK * 256;              // 1 MB
  int*   idxb = (int*)(rbuf + (size_t)NBH * NBUCK * NBUCK);
  float* sb   = (float*)(idxb + NBH * NBUCK);

  k_bsum    <<<dim3(NBUCK, NBH, 2), 256, 0, stream>>>(q, k, xbuf);
  k_sortgemm<<<dim3(32, NBH),       128, 0, stream>>>(xbuf, W, ug, rbuf);
  k_sinkhorn<<<NBH,                 512, 0, stream>>>(rbuf, idxb, sb);
  k_attn    <<<dim3(NBH, NBUCK),    256, 0, stream>>>(q, k, v, idxb, sb, out);
}

// Round 12
// 103.574 us; speedup vs baseline: 1.5092x; 1.0796x over previous
//
#include <hip/hip_runtime.h>
#include <hip/hip_bf16.h>

// Shapes (fixed by reference): b=2, h=8, t=8192, dh=128
#define T_SEQ   8192
#define DH      128
#define NBH     16
#define NBUCK   128
#define BSZ     64
#define EPSF    1e-6f

// K-tile swizzle (16B granular, proven in R5)
#define SWZ(r)  (((((r) & 7) ^ (((r) >> 3) & 7))) << 3)
// V-tile: pitch 72 ushorts (144B -> 4*d bank spread) + (d>>3)-keyed 16B XOR
#define VPITCH 72
#define VXOR(d) ((((d) >> 3) & 7) << 3)
// float4 / ushort4 compile-time component select (folds under full unroll)
#define CF4(v,c) ((c)==0 ? (v).x : (c)==1 ? (v).y : (c)==2 ? (v).z : (v).w)
#define CU4(v,c) ((c)==0 ? (v).x : (c)==1 ? (v).y : (c)==2 ? (v).z : (v).w)

typedef __attribute__((ext_vector_type(8))) __bf16 bf16x8;
typedef __attribute__((ext_vector_type(4))) float  f32x4;

static __device__ __forceinline__ unsigned short f2bf(float f) {
  __bf16 h = (__bf16)f;
  return __builtin_bit_cast(unsigned short, h);
}

// ---------------------------------------------------------------------------
// Kernel 1 (fused bsum + sortgemm): grid (128, 16), 256 threads.
// Stage A: coalesced float4 reduce of q-bucket and k-bucket -> x[256] in LDS.
// Stage B: per-bucket sortnet dot (2 threads per output, W coalesced across
// 128 lanes; W is L2/L3-resident: 256 blocks share each head's W) ->
// relu + gumbel-log -> rbuf row.
// ---------------------------------------------------------------------------
__global__ __launch_bounds__(256) void k_bsort(
    const float* __restrict__ q, const float* __restrict__ k,
    const float* __restrict__ W, const float* __restrict__ ug,
    float* __restrict__ rbuf) {
  const int u = blockIdx.x, bh = blockIdx.y;
  const int t = threadIdx.x;
  const int c4g = t & 31;           // float4 column group 0..31
  const int grp = t >> 5;           // row group 0..7 (8 rows each)

  __shared__ float4 xrq[8][32];
  __shared__ float4 xrk[8][32];
  __shared__ float  x[256];
  __shared__ float  part[256];

  {
    const size_t base = ((size_t)bh * T_SEQ + (size_t)u * BSZ + grp * 8) * DH + c4g * 4;
    float4 aq = {0.f, 0.f, 0.f, 0.f};
    float4 ak = {0.f, 0.f, 0.f, 0.f};
    #pragma unroll
    for (int r = 0; r < 8; r++) {
      float4 vq = *(const float4*)(q + base + (size_t)r * DH);
      float4 vk = *(const float4*)(k + base + (size_t)r * DH);
      aq.x += vq.x; aq.y += vq.y; aq.z += vq.z; aq.w += vq.w;
      ak.x += vk.x; ak.y += vk.y; ak.z += vk.z; ak.w += vk.w;
    }
    xrq[grp][c4g] = aq;
    xrk[grp][c4g] = ak;
  }
  __syncthreads();
  if (t < 64) {
    const int which = t >> 5;       // 0 = q half, 1 = k half
    const int cg = t & 31;
    float4 s4 = which ? xrk[0][cg] : xrq[0][cg];
    #pragma unroll
    for (int j = 1; j < 8; j++) {
      float4 o = which ? xrk[j][cg] : xrq[j][cg];
      s4.x += o.x; s4.y += o.y; s4.z += o.z; s4.w += o.w;
    }
    *(float4*)(&x[which * 128 + cg * 4]) = s4;
  }
  __syncthreads();
  {
    const int eh = t >> 7;          // 0/1: which 128-half of the 256-dot
    const int vcol = t & 127;
    const float* Wp = W + ((size_t)(bh & 7) * 256 + (size_t)eh * 128) * NBUCK + vcol;
    float racc = 0.f;
    #pragma unroll 16
    for (int e = 0; e < 128; e++) racc += x[eh * 128 + e] * Wp[(size_t)e * NBUCK];
    part[t] = racc;
  }
  __syncthreads();
  if (t < 128) {
    float R = part[t] + part[t + 128];
    R = fmaxf(R, 0.f) + EPSF;
    float gu = ug[((size_t)bh * NBUCK + u) * NBUCK + t] + EPSF;
    float g = -logf(-logf(gu) + EPSF);
    rbuf[((size_t)bh * NBUCK + u) * NBUCK + t] = (logf(R) + g) * (1.f / 0.75f);
  }
}

// ---------------------------------------------------------------------------
// Kernel 2: sinkhorn, register-resident. grid 16, 512 threads.
// ---------------------------------------------------------------------------
__global__ __launch_bounds__(512, 1) void k_sinkhorn(
    const float* __restrict__ rbuf, int* __restrict__ idxb, float* __restrict__ sb) {
  const int bh = blockIdx.x;
  const int t  = threadIdx.x;
  const int own = t >> 2;
  const int qq  = t & 3;
  __shared__ float rl[128 * 129];
  __shared__ float ca[128], ra[128];

  const float* rb = rbuf + (size_t)bh * (NBUCK * NBUCK);
  for (int i = t; i < NBUCK * NBUCK; i += 512)
    rl[(i >> 7) * 129 + (i & 127)] = rb[i];
  if (t < 128) ca[t] = 0.f;
  __syncthreads();

  float rowv[32], colv[32];
  #pragma unroll
  for (int i4 = 0; i4 < 8; i4++) {
    float4 vv = *(const float4*)(&rl[own * 129 + qq * 32 + i4 * 4]);
    rowv[i4 * 4 + 0] = vv.x; rowv[i4 * 4 + 1] = vv.y;
    rowv[i4 * 4 + 2] = vv.z; rowv[i4 * 4 + 3] = vv.w;
  }
  #pragma unroll
  for (int i = 0; i < 32; i++) colv[i] = rl[(qq * 32 + i) * 129 + own];

  for (int iter = 0; iter < 7; iter++) {
    {
      float vals[32];
      float m = -1e30f;
      #pragma unroll
      for (int i4 = 0; i4 < 8; i4++) {
        float4 cc = *(const float4*)(&ca[qq * 32 + i4 * 4]);
        vals[i4 * 4 + 0] = rowv[i4 * 4 + 0] + cc.x;
        vals[i4 * 4 + 1] = rowv[i4 * 4 + 1] + cc.y;
        vals[i4 * 4 + 2] = rowv[i4 * 4 + 2] + cc.z;
        vals[i4 * 4 + 3] = rowv[i4 * 4 + 3] + cc.w;
      }
      #pragma unroll
      for (int i = 0; i < 32; i++) m = fmaxf(m, vals[i]);
      m = fmaxf(m, __shfl_xor(m, 1));
      m = fmaxf(m, __shfl_xor(m, 2));
      float s0 = 0.f, s1 = 0.f, s2 = 0.f, s3 = 0.f;
      #pragma unroll
      for (int i = 0; i < 8; i++) {
        s0 += __expf(vals[i * 4 + 0] - m);
        s1 += __expf(vals[i * 4 + 1] - m);
        s2 += __expf(vals[i * 4 + 2] - m);
        s3 += __expf(vals[i * 4 + 3] - m);
      }
      float ss = (s0 + s1) + (s2 + s3);
      ss += __shfl_xor(ss, 1);
      ss += __shfl_xor(ss, 2);
      if (qq == 0) ra[own] = -(m + logf(ss));
    }
    __syncthreads();
    {
      float vals[32];
      float m = -1e30f;
      #pragma unroll
      for (int i4 = 0; i4 < 8; i4++) {
        float4 rr = *(const float4*)(&ra[qq * 32 + i4 * 4]);
        vals[i4 * 4 + 0] = colv[i4 * 4 + 0] + rr.x;
        vals[i4 * 4 + 1] = colv[i4 * 4 + 1] + rr.y;
        vals[i4 * 4 + 2] = colv[i4 * 4 + 2] + rr.z;
        vals[i4 * 4 + 3] = colv[i4 * 4 + 3] + rr.w;
      }
      #pragma unroll
      for (int i = 0; i < 32; i++) m = fmaxf(m, vals[i]);
      m = fmaxf(m, __shfl_xor(m, 1));
      m = fmaxf(m, __shfl_xor(m, 2));
      float s0 = 0.f, s1 = 0.f, s2 = 0.f, s3 = 0.f;
      #pragma unroll
      for (int i = 0; i < 8; i++) {
        s0 += __expf(vals[i * 4 + 0] - m);
        s1 += __expf(vals[i * 4 + 1] - m);
        s2 += __expf(vals[i * 4 + 2] - m);
        s3 += __expf(vals[i * 4 + 3] - m);
      }
      float ss = (s0 + s1) + (s2 + s3);
      ss += __shfl_xor(ss, 1);
      ss += __shfl_xor(ss, 2);
      if (qq == 0) ca[own] = -(m + logf(ss));
    }
    __syncthreads();
  }

  {
    float best = -1e30f; int bi = qq * 32;
    #pragma unroll
    for (int i = 0; i < 32; i++) {
      float val = rowv[i] + ca[qq * 32 + i];
      if (val > best) { best = val; bi = qq * 32 + i; }
    }
    #pragma unroll
    for (int d = 1; d < 4; d <<= 1) {
      float ob = __shfl_xor(best, d);
      int   oi = __shfl_xor(bi, d);
      if (ob > best || (ob == best && oi < bi)) { best = ob; bi = oi; }
    }
    if (qq == 0) {
      idxb[bh * NBUCK + own] = bi;
      sb[bh * NBUCK + own]   = expf(rl[own * 129 + bi] + ra[own] + ca[bi]);
    }
  }
}

// ---------------------------------------------------------------------------
// Kernel 3: per-bucket attention. grid (16 bh, 128 bucket), 256 threads.
// Grid transposed for XCD L2 locality (XCD = bh % 8). LDS 34816B:
//   [0,16384)     K tile [128][128], SWZ          -- dead after B2
//   [0,8192)      P [64][128], SWZ(prow)          -- after B2 (own-wave rows)
//   [8192,17408)  V half, pitch-72 + VXOR layout  -- V1 after B2, V2 after B4
// ---------------------------------------------------------------------------
__global__ __launch_bounds__(256) void k_attn(
    const float* __restrict__ q, const float* __restrict__ k, const float* __restrict__ v,
    const int* __restrict__ idxb, const float* __restrict__ sb, float* __restrict__ out) {
  const int bh = blockIdx.x;    // transposed: bh on x -> XCD = bh % 8
  const int u  = blockIdx.y;
  const int t  = threadIdx.x;
  const int lane = t & 63;
  const int w  = t >> 6;
  const int l15 = lane & 15;
  const int lgp = lane >> 4;

  __shared__ uint4 smem4[2176];   // 34816 B = 17408 ushorts
  unsigned short* sm = (unsigned short*)smem4;
  #define VBASE 8192

  const int   vidx = idxb[bh * NBUCK + u];
  const float sval = sb[bh * NBUCK + u];
  const size_t hb = (size_t)bh * (T_SEQ * DH);
  const float* qg = q + hb;
  const float* kg = k + hb;
  const float* vg = v + hb;

  // micro-tile coords for V staging: 4 j-rows x 8 d-cols per thread
  const int vj0 = (t >> 4) * 4;        // 0..60
  const int vd0 = (t & 15) * 8;        // 0..120

  // ---- K -> LDS [0,16384) (interleaved load/cvt/store) ----
  #pragma unroll
  for (int it = 0; it < 16; it++) {
    int i = it * 256 + t;
    int row = i >> 5;
    int c4 = (i & 31) << 2;
    int grow = (row < 64) ? (vidx * BSZ + row) : (u * BSZ + (row - 64));
    float4 val = *(const float4*)(kg + (size_t)grow * DH + c4);
    ushort4 hh;
    hh.x = f2bf(val.x); hh.y = f2bf(val.y); hh.z = f2bf(val.z); hh.w = f2bf(val.w);
    *(ushort4*)(sm + (((row * 128 + c4) ^ SWZ(row)))) = hh;
  }
  // ---- Q fragments direct global -> reg ----
  bf16x8 aQ[4];
  {
    int qrow = u * BSZ + w * 16 + l15;
    const float* qp = qg + (size_t)qrow * DH + lgp * 8;
    #pragma unroll
    for (int kk = 0; kk < 4; kk++) {
      float4 v0 = *(const float4*)(qp + kk * 32);
      float4 v1 = *(const float4*)(qp + kk * 32 + 4);
      bf16x8 f;
      f[0] = (__bf16)v0.x; f[1] = (__bf16)v0.y; f[2] = (__bf16)v0.z; f[3] = (__bf16)v0.w;
      f[4] = (__bf16)v1.x; f[5] = (__bf16)v1.y; f[6] = (__bf16)v1.z; f[7] = (__bf16)v1.w;
      aQ[kk] = f;
    }
  }
  // ---- issue V half-1 loads (4 rows x 8 cols, held in regs until B2) ----
  float4 vpre[4][2];
  #pragma unroll
  for (int r = 0; r < 4; r++) {
    const float* vp = vg + (size_t)(vidx * BSZ + vj0 + r) * DH + vd0;
    vpre[r][0] = *(const float4*)(vp);
    vpre[r][1] = *(const float4*)(vp + 4);
  }
  __syncthreads();   // B1: K staged

  // ---- S = Q K^T ----
  f32x4 accS[8];
  __builtin_amdgcn_s_setprio(1);
  #pragma unroll
  for (int n = 0; n < 8; n++) {
    f32x4 acc = {0.f, 0.f, 0.f, 0.f};
    #pragma unroll
    for (int kk = 0; kk < 4; kk++) {
      int row = n * 16 + l15;
      int c0 = lgp * 8 + kk * 32;
      bf16x8 bK = *(const bf16x8*)(sm + ((row * 128 + c0) ^ SWZ(row)));
      acc = __builtin_amdgcn_mfma_f32_16x16x32_bf16(aQ[kk], bK, acc, 0, 0, 0);
    }
    accS[n] = acc;
  }
  __builtin_amdgcn_s_setprio(0);

  // ---- softmax per row ----
  float pval[8][4];
  float lsum[4];
  #pragma unroll
  for (int r = 0; r < 4; r++) {
    float mm = -1e30f;
    #pragma unroll
    for (int n = 0; n < 8; n++) {
      float lg2 = accS[n][r] * 0.03125f * (n < 4 ? sval : 1.0f);
      pval[n][r] = lg2;
      mm = fmaxf(mm, lg2);
    }
    mm = fmaxf(mm, __shfl_xor(mm, 1));
    mm = fmaxf(mm, __shfl_xor(mm, 2));
    mm = fmaxf(mm, __shfl_xor(mm, 4));
    mm = fmaxf(mm, __shfl_xor(mm, 8));
    float ss = 0.f;
    #pragma unroll
    for (int n = 0; n < 8; n++) {
      float p = __expf(pval[n][r] - mm);
      ss += p;
      pval[n][r] = p * (n < 4 ? sval : 1.0f);
    }
    ss += __shfl_xor(ss, 1);
    ss += __shfl_xor(ss, 2);
    ss += __shfl_xor(ss, 4);
    ss += __shfl_xor(ss, 8);
    lsum[r] = ss;
  }

  __syncthreads();   // B2: K dead; [0,16384) reusable

  // ---- write P (own wave rows) into [0,8192) ----
  #pragma unroll
  for (int n = 0; n < 8; n++) {
    #pragma unroll
    for (int r = 0; r < 4; r++) {
      int prow = w * 16 + lgp * 4 + r;
      int pcol = n * 16 + l15;
      sm[(prow * 128 + pcol) ^ SWZ(prow)] = f2bf(pval[n][r]);
    }
  }
  // ---- V half-1 regs -> LDS (micro-transpose: ushort4 along j) ----
  #pragma unroll
  for (int x = 0; x < 8; x++) {
    int d = vd0 + x;
    int h = x >> 2, c = x & 3;
    ushort4 val;
    val.x = f2bf(CF4(vpre[0][h], c));
    val.y = f2bf(CF4(vpre[1][h], c));
    val.z = f2bf(CF4(vpre[2][h], c));
    val.w = f2bf(CF4(vpre[3][h], c));
    *(ushort4*)(sm + VBASE + d * VPITCH + (vj0 ^ VXOR(d))) = val;
  }
  // ---- issue V half-2 loads (convert+pack immediately; 16 VGPR B2->B4) ----
  ushort4 v2p[4][2];
  #pragma unroll
  for (int r = 0; r < 4; r++) {
    const float* vp = vg + (size_t)(u * BSZ + vj0 + r) * DH + vd0;
    #pragma unroll
    for (int h = 0; h < 2; h++) {
      float4 ld = *(const float4*)(vp + h * 4);
      v2p[r][h].x = f2bf(ld.x); v2p[r][h].y = f2bf(ld.y);
      v2p[r][h].z = f2bf(ld.z); v2p[r][h].w = f2bf(ld.w);
    }
  }
  __syncthreads();   // B3: P + V1 ready

  // ---- aP fragments (own-wave rows) ----
  bf16x8 aP[4];
  #pragma unroll
  for (int kk = 0; kk < 4; kk++) {
    int prow = w * 16 + l15;
    int c0 = lgp * 8 + kk * 32;
    aP[kk] = *(const bf16x8*)(sm + ((prow * 128 + c0) ^ SWZ(prow)));
  }

  // ---- PV part 1 (j = 0..63) ----
  f32x4 accO[8];
  __builtin_amdgcn_s_setprio(1);
  #pragma unroll
  for (int n = 0; n < 8; n++) {
    f32x4 acc = {0.f, 0.f, 0.f, 0.f};
    #pragma unroll
    for (int kk = 0; kk < 2; kk++) {
      int d = n * 16 + l15;
      int jj0 = lgp * 8 + kk * 32;
      bf16x8 bV = *(const bf16x8*)(sm + VBASE + d * VPITCH + (jj0 ^ VXOR(d)));
      acc = __builtin_amdgcn_mfma_f32_16x16x32_bf16(aP[kk], bV, acc, 0, 0, 0);
    }
    accO[n] = acc;
  }
  __builtin_amdgcn_s_setprio(0);
  __syncthreads();   // B4: done reading V1

  // ---- V half-2 regs -> LDS (same micro-transpose) ----
  #pragma unroll
  for (int x = 0; x < 8; x++) {
    int d = vd0 + x;
    int h = x >> 2, c = x & 3;
    ushort4 val;
    val.x = CU4(v2p[0][h], c);
    val.y = CU4(v2p[1][h], c);
    val.z = CU4(v2p[2][h], c);
    val.w = CU4(v2p[3][h], c);
    *(ushort4*)(sm + VBASE + d * VPITCH + (vj0 ^ VXOR(d))) = val;
  }
  __syncthreads();   // B5: V2 ready

  float invl[4];
  #pragma unroll
  for (int r = 0; r < 4; r++) invl[r] = 1.0f / lsum[r];

  // ---- PV part 2 (j = 64..127) + store ----
  __builtin_amdgcn_s_setprio(1);
  #pragma unroll
  for (int n = 0; n < 8; n++) {
    f32x4 acc = accO[n];
    #pragma unroll
    for (int kk = 2; kk < 4; kk++) {
      int d = n * 16 + l15;
      int jj0 = lgp * 8 + (kk - 2) * 32;
      bf16x8 bV = *(const bf16x8*)(sm + VBASE + d * VPITCH + (jj0 ^ VXOR(d)));
      acc = __builtin_amdgcn_mfma_f32_16x16x32_bf16(aP[kk], bV, acc, 0, 0, 0);
    }
    #pragma unroll
    for (int r = 0; r < 4; r++) {
      int i2 = w * 16 + lgp * 4 + r;
      int d = n * 16 + l15;
      out[((size_t)bh * T_SEQ + (size_t)u * BSZ + i2) * DH + d] = acc[r] * invl[r];
    }
  }
  __builtin_amdgcn_s_setprio(0);
}

// ---------------------------------------------------------------------------
extern "C" void kernel_launch(void* const* d_in, const int* in_sizes, int n_in,
                              void* d_out, int out_size, void* d_ws, size_t ws_size,
                              hipStream_t stream) {
  (void)in_sizes; (void)n_in; (void)out_size; (void)ws_size;
  const float* q  = (const float*)d_in[0];
  const float* k  = (const float*)d_in[1];
  const float* v  = (const float*)d_in[2];
  const float* W  = (const float*)d_in[3];
  const float* ug = (const float*)d_in[4];
  float* out = (float*)d_out;

  float* rbuf = (float*)d_ws;                                  // 1 MB
  int*   idxb = (int*)(rbuf + (size_t)NBH * NBUCK * NBUCK);
  float* sb   = (float*)(idxb + NBH * NBUCK);

  k_bsort   <<<dim3(NBUCK, NBH), 256, 0, stream>>>(q, k, W, ug, rbuf);
  k_sinkhorn<<<NBH,              512, 0, stream>>>(rbuf, idxb, sb);
  k_attn    <<<dim3(NBH, NBUCK), 256, 0, stream>>>(q, k, v, idxb, sb, out);
}

// Round 13
// 103.099 us; speedup vs baseline: 1.5162x; 1.0046x over previous
//
#include <hip/hip_runtime.h>
#include <hip/hip_bf16.h>

// Shapes (fixed by reference): b=2, h=8, t=8192, dh=128
#define T_SEQ   8192
#define DH      128
#define NBH     16
#define NBUCK   128
#define BSZ     64
#define EPSF    1e-6f

// 16B-granular XOR swizzle (keyed on low 6 bits of row index)
#define SWZ(r)  (((((r) & 7) ^ (((r) >> 3) & 7))) << 3)
// float4 / ushort4 compile-time component select (folds under full unroll)
#define CF4(v,c) ((c)==0 ? (v).x : (c)==1 ? (v).y : (c)==2 ? (v).z : (v).w)
#define CU4(v,c) ((c)==0 ? (v).x : (c)==1 ? (v).y : (c)==2 ? (v).z : (v).w)

typedef __attribute__((ext_vector_type(8))) __bf16 bf16x8;
typedef __attribute__((ext_vector_type(4))) float  f32x4;

static __device__ __forceinline__ unsigned short f2bf(float f) {
  __bf16 h = (__bf16)f;
  return __builtin_bit_cast(unsigned short, h);
}

// ---------------------------------------------------------------------------
// Kernel 1 (fused bsum + sortgemm): grid (128, 16), 256 threads.
// ---------------------------------------------------------------------------
__global__ __launch_bounds__(256) void k_bsort(
    const float* __restrict__ q, const float* __restrict__ k,
    const float* __restrict__ W, const float* __restrict__ ug,
    float* __restrict__ rbuf) {
  const int u = blockIdx.x, bh = blockIdx.y;
  const int t = threadIdx.x;
  const int c4g = t & 31;           // float4 column group 0..31
  const int grp = t >> 5;           // row group 0..7 (8 rows each)

  __shared__ float4 xrq[8][32];
  __shared__ float4 xrk[8][32];
  __shared__ float  x[256];
  __shared__ float  part[256];

  {
    const size_t base = ((size_t)bh * T_SEQ + (size_t)u * BSZ + grp * 8) * DH + c4g * 4;
    float4 aq = {0.f, 0.f, 0.f, 0.f};
    float4 ak = {0.f, 0.f, 0.f, 0.f};
    #pragma unroll
    for (int r = 0; r < 8; r++) {
      float4 vq = *(const float4*)(q + base + (size_t)r * DH);
      float4 vk = *(const float4*)(k + base + (size_t)r * DH);
      aq.x += vq.x; aq.y += vq.y; aq.z += vq.z; aq.w += vq.w;
      ak.x += vk.x; ak.y += vk.y; ak.z += vk.z; ak.w += vk.w;
    }
    xrq[grp][c4g] = aq;
    xrk[grp][c4g] = ak;
  }
  __syncthreads();
  if (t < 64) {
    const int which = t >> 5;       // 0 = q half, 1 = k half
    const int cg = t & 31;
    float4 s4 = which ? xrk[0][cg] : xrq[0][cg];
    #pragma unroll
    for (int j = 1; j < 8; j++) {
      float4 o = which ? xrk[j][cg] : xrq[j][cg];
      s4.x += o.x; s4.y += o.y; s4.z += o.z; s4.w += o.w;
    }
    *(float4*)(&x[which * 128 + cg * 4]) = s4;
  }
  __syncthreads();
  {
    const int eh = t >> 7;          // 0/1: which 128-half of the 256-dot
    const int vcol = t & 127;
    const float* Wp = W + ((size_t)(bh & 7) * 256 + (size_t)eh * 128) * NBUCK + vcol;
    float racc = 0.f;
    #pragma unroll 16
    for (int e = 0; e < 128; e++) racc += x[eh * 128 + e] * Wp[(size_t)e * NBUCK];
    part[t] = racc;
  }
  __syncthreads();
  if (t < 128) {
    float R = part[t] + part[t + 128];
    R = fmaxf(R, 0.f) + EPSF;
    float gu = ug[((size_t)bh * NBUCK + u) * NBUCK + t] + EPSF;
    float g = -logf(-logf(gu) + EPSF);
    rbuf[((size_t)bh * NBUCK + u) * NBUCK + t] = (logf(R) + g) * (1.f / 0.75f);
  }
}

// ---------------------------------------------------------------------------
// Kernel 2: sinkhorn, register-resident. grid 16, 512 threads.
// ---------------------------------------------------------------------------
__global__ __launch_bounds__(512, 1) void k_sinkhorn(
    const float* __restrict__ rbuf, int* __restrict__ idxb, float* __restrict__ sb) {
  const int bh = blockIdx.x;
  const int t  = threadIdx.x;
  const int own = t >> 2;
  const int qq  = t & 3;
  __shared__ float rl[128 * 129];
  __shared__ float ca[128], ra[128];

  const float* rb = rbuf + (size_t)bh * (NBUCK * NBUCK);
  for (int i = t; i < NBUCK * NBUCK; i += 512)
    rl[(i >> 7) * 129 + (i & 127)] = rb[i];
  if (t < 128) ca[t] = 0.f;
  __syncthreads();

  float rowv[32], colv[32];
  #pragma unroll
  for (int i4 = 0; i4 < 8; i4++) {
    float4 vv = *(const float4*)(&rl[own * 129 + qq * 32 + i4 * 4]);
    rowv[i4 * 4 + 0] = vv.x; rowv[i4 * 4 + 1] = vv.y;
    rowv[i4 * 4 + 2] = vv.z; rowv[i4 * 4 + 3] = vv.w;
  }
  #pragma unroll
  for (int i = 0; i < 32; i++) colv[i] = rl[(qq * 32 + i) * 129 + own];

  for (int iter = 0; iter < 7; iter++) {
    {
      float vals[32];
      float m = -1e30f;
      #pragma unroll
      for (int i4 = 0; i4 < 8; i4++) {
        float4 cc = *(const float4*)(&ca[qq * 32 + i4 * 4]);
        vals[i4 * 4 + 0] = rowv[i4 * 4 + 0] + cc.x;
        vals[i4 * 4 + 1] = rowv[i4 * 4 + 1] + cc.y;
        vals[i4 * 4 + 2] = rowv[i4 * 4 + 2] + cc.z;
        vals[i4 * 4 + 3] = rowv[i4 * 4 + 3] + cc.w;
      }
      #pragma unroll
      for (int i = 0; i < 32; i++) m = fmaxf(m, vals[i]);
      m = fmaxf(m, __shfl_xor(m, 1));
      m = fmaxf(m, __shfl_xor(m, 2));
      float s0 = 0.f, s1 = 0.f, s2 = 0.f, s3 = 0.f;
      #pragma unroll
      for (int i = 0; i < 8; i++) {
        s0 += __expf(vals[i * 4 + 0] - m);
        s1 += __expf(vals[i * 4 + 1] - m);
        s2 += __expf(vals[i * 4 + 2] - m);
        s3 += __expf(vals[i * 4 + 3] - m);
      }
      float ss = (s0 + s1) + (s2 + s3);
      ss += __shfl_xor(ss, 1);
      ss += __shfl_xor(ss, 2);
      if (qq == 0) ra[own] = -(m + logf(ss));
    }
    __syncthreads();
    {
      float vals[32];
      float m = -1e30f;
      #pragma unroll
      for (int i4 = 0; i4 < 8; i4++) {
        float4 rr = *(const float4*)(&ra[qq * 32 + i4 * 4]);
        vals[i4 * 4 + 0] = colv[i4 * 4 + 0] + rr.x;
        vals[i4 * 4 + 1] = colv[i4 * 4 + 1] + rr.y;
        vals[i4 * 4 + 2] = colv[i4 * 4 + 2] + rr.z;
        vals[i4 * 4 + 3] = colv[i4 * 4 + 3] + rr.w;
      }
      #pragma unroll
      for (int i = 0; i < 32; i++) m = fmaxf(m, vals[i]);
      m = fmaxf(m, __shfl_xor(m, 1));
      m = fmaxf(m, __shfl_xor(m, 2));
      float s0 = 0.f, s1 = 0.f, s2 = 0.f, s3 = 0.f;
      #pragma unroll
      for (int i = 0; i < 8; i++) {
        s0 += __expf(vals[i * 4 + 0] - m);
        s1 += __expf(vals[i * 4 + 1] - m);
        s2 += __expf(vals[i * 4 + 2] - m);
        s3 += __expf(vals[i * 4 + 3] - m);
      }
      float ss = (s0 + s1) + (s2 + s3);
      ss += __shfl_xor(ss, 1);
      ss += __shfl_xor(ss, 2);
      if (qq == 0) ca[own] = -(m + logf(ss));
    }
    __syncthreads();
  }

  {
    float best = -1e30f; int bi = qq * 32;
    #pragma unroll
    for (int i = 0; i < 32; i++) {
      float val = rowv[i] + ca[qq * 32 + i];
      if (val > best) { best = val; bi = qq * 32 + i; }
    }
    #pragma unroll
    for (int d = 1; d < 4; d <<= 1) {
      float ob = __shfl_xor(best, d);
      int   oi = __shfl_xor(bi, d);
      if (ob > best || (ob == best && oi < bi)) { best = ob; bi = oi; }
    }
    if (qq == 0) {
      idxb[bh * NBUCK + own] = bi;
      sb[bh * NBUCK + own]   = expf(rl[own * 129 + bi] + ra[own] + ca[bi]);
    }
  }
}

// ---------------------------------------------------------------------------
// Kernel 3: per-bucket attention. grid (16 bh, 128 bucket), 256 threads.
// Grid transposed for XCD L2 locality (XCD = bh % 8).
// LDS 32768 B -> 5 blocks/CU (VGPR 80 allows 20 waves/CU). Region map:
//   [0,16384)     K tile [128][128], SWZ        -- dead after B2
//   [0,8192)      P [64][128], SWZ(prow)        -- after B2 (own-wave rows)
//   [8192,16384)  V half [128d][64j], pitch 64, j ^ SWZ(d)
//                 (bank = j0/2: micro-transpose writes ~2-4-way, reads ~2-way)
// ---------------------------------------------------------------------------
__global__ __launch_bounds__(256) void k_attn(
    const float* __restrict__ q, const float* __restrict__ k, const float* __restrict__ v,
    const int* __restrict__ idxb, const float* __restrict__ sb, float* __restrict__ out) {
  const int bh = blockIdx.x;    // transposed: bh on x -> XCD = bh % 8
  const int u  = blockIdx.y;
  const int t  = threadIdx.x;
  const int lane = t & 63;
  const int w  = t >> 6;
  const int l15 = lane & 15;
  const int lgp = lane >> 4;

  __shared__ uint4 smem4[2048];   // 32768 B = 16384 ushorts -> 5 blocks/CU
  unsigned short* sm = (unsigned short*)smem4;
  #define VBASE 8192

  const int   vidx = idxb[bh * NBUCK + u];
  const float sval = sb[bh * NBUCK + u];
  const size_t hb = (size_t)bh * (T_SEQ * DH);
  const float* qg = q + hb;
  const float* kg = k + hb;
  const float* vg = v + hb;

  // micro-tile coords for V staging: 4 j-rows x 8 d-cols per thread
  const int vj0 = (t >> 4) * 4;        // 0..60
  const int vd0 = (t & 15) * 8;        // 0..120

  // ---- K -> LDS [0,16384) (interleaved load/cvt/store) ----
  #pragma unroll
  for (int it = 0; it < 16; it++) {
    int i = it * 256 + t;
    int row = i >> 5;
    int c4 = (i & 31) << 2;
    int grow = (row < 64) ? (vidx * BSZ + row) : (u * BSZ + (row - 64));
    float4 val = *(const float4*)(kg + (size_t)grow * DH + c4);
    ushort4 hh;
    hh.x = f2bf(val.x); hh.y = f2bf(val.y); hh.z = f2bf(val.z); hh.w = f2bf(val.w);
    *(ushort4*)(sm + (((row * 128 + c4) ^ SWZ(row)))) = hh;
  }
  // ---- Q fragments direct global -> reg ----
  bf16x8 aQ[4];
  {
    int qrow = u * BSZ + w * 16 + l15;
    const float* qp = qg + (size_t)qrow * DH + lgp * 8;
    #pragma unroll
    for (int kk = 0; kk < 4; kk++) {
      float4 v0 = *(const float4*)(qp + kk * 32);
      float4 v1 = *(const float4*)(qp + kk * 32 + 4);
      bf16x8 f;
      f[0] = (__bf16)v0.x; f[1] = (__bf16)v0.y; f[2] = (__bf16)v0.z; f[3] = (__bf16)v0.w;
      f[4] = (__bf16)v1.x; f[5] = (__bf16)v1.y; f[6] = (__bf16)v1.z; f[7] = (__bf16)v1.w;
      aQ[kk] = f;
    }
  }
  // ---- issue V half-1 loads (4 rows x 8 cols, held in regs until B2) ----
  float4 vpre[4][2];
  #pragma unroll
  for (int r = 0; r < 4; r++) {
    const float* vp = vg + (size_t)(vidx * BSZ + vj0 + r) * DH + vd0;
    vpre[r][0] = *(const float4*)(vp);
    vpre[r][1] = *(const float4*)(vp + 4);
  }
  __syncthreads();   // B1: K staged

  // ---- S = Q K^T ----
  f32x4 accS[8];
  __builtin_amdgcn_s_setprio(1);
  #pragma unroll
  for (int n = 0; n < 8; n++) {
    f32x4 acc = {0.f, 0.f, 0.f, 0.f};
    #pragma unroll
    for (int kk = 0; kk < 4; kk++) {
      int row = n * 16 + l15;
      int c0 = lgp * 8 + kk * 32;
      bf16x8 bK = *(const bf16x8*)(sm + ((row * 128 + c0) ^ SWZ(row)));
      acc = __builtin_amdgcn_mfma_f32_16x16x32_bf16(aQ[kk], bK, acc, 0, 0, 0);
    }
    accS[n] = acc;
  }
  __builtin_amdgcn_s_setprio(0);

  // ---- softmax per row ----
  float pval[8][4];
  float lsum[4];
  #pragma unroll
  for (int r = 0; r < 4; r++) {
    float mm = -1e30f;
    #pragma unroll
    for (int n = 0; n < 8; n++) {
      float lg2 = accS[n][r] * 0.03125f * (n < 4 ? sval : 1.0f);
      pval[n][r] = lg2;
      mm = fmaxf(mm, lg2);
    }
    mm = fmaxf(mm, __shfl_xor(mm, 1));
    mm = fmaxf(mm, __shfl_xor(mm, 2));
    mm = fmaxf(mm, __shfl_xor(mm, 4));
    mm = fmaxf(mm, __shfl_xor(mm, 8));
    float ss = 0.f;
    #pragma unroll
    for (int n = 0; n < 8; n++) {
      float p = __expf(pval[n][r] - mm);
      ss += p;
      pval[n][r] = p * (n < 4 ? sval : 1.0f);
    }
    ss += __shfl_xor(ss, 1);
    ss += __shfl_xor(ss, 2);
    ss += __shfl_xor(ss, 4);
    ss += __shfl_xor(ss, 8);
    lsum[r] = ss;
  }

  __syncthreads();   // B2: K dead; [0,16384) reusable

  // ---- write P (own wave rows) into [0,8192) ----
  #pragma unroll
  for (int n = 0; n < 8; n++) {
    #pragma unroll
    for (int r = 0; r < 4; r++) {
      int prow = w * 16 + lgp * 4 + r;
      int pcol = n * 16 + l15;
      sm[(prow * 128 + pcol) ^ SWZ(prow)] = f2bf(pval[n][r]);
    }
  }
  // ---- V half-1 regs -> LDS (micro-transpose: ushort4 along j) ----
  #pragma unroll
  for (int x = 0; x < 8; x++) {
    int d = vd0 + x;
    int h = x >> 2, c = x & 3;
    ushort4 val;
    val.x = f2bf(CF4(vpre[0][h], c));
    val.y = f2bf(CF4(vpre[1][h], c));
    val.z = f2bf(CF4(vpre[2][h], c));
    val.w = f2bf(CF4(vpre[3][h], c));
    *(ushort4*)(sm + VBASE + d * 64 + (vj0 ^ SWZ(d))) = val;
  }
  // ---- issue V half-2 loads (convert+pack immediately; 16 VGPR B2->B4) ----
  ushort4 v2p[4][2];
  #pragma unroll
  for (int r = 0; r < 4; r++) {
    const float* vp = vg + (size_t)(u * BSZ + vj0 + r) * DH + vd0;
    #pragma unroll
    for (int h = 0; h < 2; h++) {
      float4 ld = *(const float4*)(vp + h * 4);
      v2p[r][h].x = f2bf(ld.x); v2p[r][h].y = f2bf(ld.y);
      v2p[r][h].z = f2bf(ld.z); v2p[r][h].w = f2bf(ld.w);
    }
  }
  __syncthreads();   // B3: P + V1 ready

  // ---- aP fragments (own-wave rows) ----
  bf16x8 aP[4];
  #pragma unroll
  for (int kk = 0; kk < 4; kk++) {
    int prow = w * 16 + l15;
    int c0 = lgp * 8 + kk * 32;
    aP[kk] = *(const bf16x8*)(sm + ((prow * 128 + c0) ^ SWZ(prow)));
  }

  // ---- PV part 1 (j = 0..63) ----
  f32x4 accO[8];
  __builtin_amdgcn_s_setprio(1);
  #pragma unroll
  for (int n = 0; n < 8; n++) {
    f32x4 acc = {0.f, 0.f, 0.f, 0.f};
    #pragma unroll
    for (int kk = 0; kk < 2; kk++) {
      int d = n * 16 + l15;
      int jj0 = lgp * 8 + kk * 32;
      bf16x8 bV = *(const bf16x8*)(sm + VBASE + d * 64 + (jj0 ^ SWZ(d)));
      acc = __builtin_amdgcn_mfma_f32_16x16x32_bf16(aP[kk], bV, acc, 0, 0, 0);
    }
    accO[n] = acc;
  }
  __builtin_amdgcn_s_setprio(0);
  __syncthreads();   // B4: done reading V1

  // ---- V half-2 regs -> LDS (same micro-transpose) ----
  #pragma unroll
  for (int x = 0; x < 8; x++) {
    int d = vd0 + x;
    int h = x >> 2, c = x & 3;
    ushort4 val;
    val.x = CU4(v2p[0][h], c);
    val.y = CU4(v2p[1][h], c);
    val.z = CU4(v2p[2][h], c);
    val.w = CU4(v2p[3][h], c);
    *(ushort4*)(sm + VBASE + d * 64 + (vj0 ^ SWZ(d))) = val;
  }
  __syncthreads();   // B5: V2 ready

  float invl[4];
  #pragma unroll
  for (int r = 0; r < 4; r++) invl[r] = 1.0f / lsum[r];

  // ---- PV part 2 (j = 64..127) + store ----
  __builtin_amdgcn_s_setprio(1);
  #pragma unroll
  for (int n = 0; n < 8; n++) {
    f32x4 acc = accO[n];
    #pragma unroll
    for (int kk = 2; kk < 4; kk++) {
      int d = n * 16 + l15;
      int jj0 = lgp * 8 + (kk - 2) * 32;
      bf16x8 bV = *(const bf16x8*)(sm + VBASE + d * 64 + (jj0 ^ SWZ(d)));
      acc = __builtin_amdgcn_mfma_f32_16x16x32_bf16(aP[kk], bV, acc, 0, 0, 0);
    }
    #pragma unroll
    for (int r = 0; r < 4; r++) {
      int i2 = w * 16 + lgp * 4 + r;
      int d = n * 16 + l15;
      out[((size_t)bh * T_SEQ + (size_t)u * BSZ + i2) * DH + d] = acc[r] * invl[r];
    }
  }
  __builtin_amdgcn_s_setprio(0);
}

// ---------------------------------------------------------------------------
extern "C" void kernel_launch(void* const* d_in, const int* in_sizes, int n_in,
                              void* d_out, int out_size, void* d_ws, size_t ws_size,
                              hipStream_t stream) {
  (void)in_sizes; (void)n_in; (void)out_size; (void)ws_size;
  const float* q  = (const float*)d_in[0];
  const float* k  = (const float*)d_in[1];
  const float* v  = (const float*)d_in[2];
  const float* W  = (const float*)d_in[3];
  const float* ug = (const float*)d_in[4];
  float* out = (float*)d_out;

  float* rbuf = (float*)d_ws;                                  // 1 MB
  int*   idxb = (int*)(rbuf + (size_t)NBH * NBUCK * NBUCK);
  float* sb   = (float*)(idxb + NBH * NBUCK);

  k_bsort   <<<dim3(NBUCK, NBH), 256, 0, stream>>>(q, k, W, ug, rbuf);
  k_sinkhorn<<<NBH,              512, 0, stream>>>(rbuf, idxb, sb);
  k_attn    <<<dim3(NBH, NBUCK), 256, 0, stream>>>(q, k, v, idxb, sb, out);
}